// Round 2
// baseline (496.888 us; speedup 1.0000x reference)
//
#include <hip/hip_runtime.h>

// ---------------------------------------------------------------------------
// FlashMMSequenceMixing (Hyena-style): B=8, L=2048, D=768, ORDER=128, FFT=4096
// R8 -> R9 (fft_conv was top dispatch: 91us, VALU 44%, HBM 27%, occ 40%):
//  1) FFT LDS shrunk 34816 -> 32768 B exactly (XOR swizzle col^=row&15 instead
//     of 272/17 stride padding; bank cost identical: 8B accesses are 4-beat
//     minimum either way) -> 5 blocks/CU (was 4), launch_bounds(256,5).
//  2) Twiddle factors from precomputed tables (d_Tw1[256][16], d_Tw2[16][16],
//     __device__ globals, init kernel) instead of per-call sincos + serial
//     cmul power chain: ~-400 VALU inst/thread + kills 4 serial dep chains.
//     Inverse FFT uses conjugate-multiply (cmulc) on the same tables.
//  3) 1/4096 irfft normalization folded into Kf at filter_fft.
//  4) filter_k: 512 blocks x 4 rows (was 256 x 8) -> 2x TLP for its serial
//     128-iter accumulation loops (1 wave/SIMD -> 2).
// GEMM (gemm256_kernel) unchanged: needs its own counters next round.
// ---------------------------------------------------------------------------

typedef __bf16 bf16x8 __attribute__((ext_vector_type(8)));
typedef float  f32x4  __attribute__((ext_vector_type(4)));

#define AS1 __attribute__((address_space(1)))
#define AS3 __attribute__((address_space(3)))
#define GLD16(gp, lp) __builtin_amdgcn_global_load_lds((AS1 void*)(void*)(gp), (AS3 void*)(void*)(lp), 16, 0, 0)

// compiler-visible fences (memory clobber pins LDS/global ops to program order)
#define LGKM_BAR       __asm__ __volatile__("s_waitcnt lgkmcnt(0)\n\ts_barrier" ::: "memory")
#define VM_LGKM_BAR(N) __asm__ __volatile__("s_waitcnt vmcnt(" #N ") lgkmcnt(0)\n\ts_barrier" ::: "memory")

__device__ __forceinline__ unsigned short f2b(float f) {
    unsigned u = __builtin_bit_cast(unsigned, f);
    unsigned r = (u + 0x7fffu + ((u >> 16) & 1u)) >> 16;
    return (unsigned short)r;
}
__device__ __forceinline__ float b2f(unsigned short h) {
    unsigned u = ((unsigned)h) << 16;
    return __builtin_bit_cast(float, u);
}
__device__ __forceinline__ float b2f_lo(unsigned u) {
    return __builtin_bit_cast(float, u << 16);
}
__device__ __forceinline__ float b2f_hi(unsigned u) {
    return __builtin_bit_cast(float, u & 0xffff0000u);
}

__device__ __forceinline__ float2 cmul(float2 a, float2 b) {
    return make_float2(a.x * b.x - a.y * b.y, a.x * b.y + a.y * b.x);
}
__device__ __forceinline__ float2 cmulc(float2 a, float2 b) {  // a * conj(b)
    return make_float2(a.x * b.x + a.y * b.y, a.y * b.x - a.x * b.y);
}
__device__ __forceinline__ float2 cadd(float2 a, float2 b) { return make_float2(a.x + b.x, a.y + b.y); }
__device__ __forceinline__ float2 csub(float2 a, float2 b) { return make_float2(a.x - b.x, a.y - b.y); }

// ------------------------- twiddle tables ----------------------------------
#define TWO_PI 6.283185307179586f
__device__ float2 d_Tw1[4096];   // [t][k] = exp(-i 2pi t k / 4096), t<256, k<16
__device__ float2 d_Tw2[256];    // [lo][k] = exp(-i 2pi lo k / 256), lo<16, k<16

__global__ __launch_bounds__(256) void twiddle_init_kernel() {
    const int i = blockIdx.x * 256 + threadIdx.x;   // grid 17*256 = 4352
    if (i < 4096) {
        const int tt = i >> 4, k = i & 15;
        float s, c;
        __sincosf(-(float)(tt * k) * (TWO_PI / 4096.0f), &s, &c);
        d_Tw1[i] = make_float2(c, s);
    } else {
        const int j = i - 4096;
        const int lo = j >> 4, k = j & 15;
        float s, c;
        __sincosf(-(float)(lo * k) * (TWO_PI / 256.0f), &s, &c);
        d_Tw2[j] = make_float2(c, s);
    }
}

// ------------------------- 16-point register DFT ---------------------------
#define BFLY(i,j)   { float2 ta=x[i], tb=x[j]; x[i]=cadd(ta,tb); x[j]=csub(ta,tb); }
#define BFLYW(i,j,w){ float2 ta=x[i], tb=x[j]; x[i]=cadd(ta,tb); x[j]=cmul(csub(ta,tb),(w)); }
#define BFLYI(i,j)  { float2 ta=x[i], tb=x[j]; x[i]=cadd(ta,tb); float2 tt=csub(ta,tb); x[j]=make_float2(-dd*tt.y, dd*tt.x); }
#define CSWAP(i,j)  { float2 tt=x[i]; x[i]=x[j]; x[j]=tt; }

template<int DIR, bool UZ>
__device__ __forceinline__ void dft16(float2* x) {
    const float dd = (float)DIR;
    const float C1 = 0.92387953251128674f, S1 = 0.38268343236508977f, R2 = 0.70710678118654752f;
    const float2 W1 = make_float2( C1, dd*S1);
    const float2 W2 = make_float2( R2, dd*R2);
    const float2 W3 = make_float2( S1, dd*C1);
    const float2 W5 = make_float2(-S1, dd*C1);
    const float2 W6 = make_float2(-R2, dd*R2);
    const float2 W7 = make_float2(-C1, dd*S1);
    if (UZ) {
        x[8]  = x[0];
        x[9]  = cmul(x[1], W1);
        x[10] = cmul(x[2], W2);
        x[11] = cmul(x[3], W3);
        x[12] = make_float2(-dd*x[4].y, dd*x[4].x);
        x[13] = cmul(x[5], W5);
        x[14] = cmul(x[6], W6);
        x[15] = cmul(x[7], W7);
    } else {
        BFLY(0,8); BFLYW(1,9,W1); BFLYW(2,10,W2); BFLYW(3,11,W3);
        BFLYI(4,12); BFLYW(5,13,W5); BFLYW(6,14,W6); BFLYW(7,15,W7);
    }
    BFLY(0,4);  BFLYW(1,5,W2);  BFLYI(2,6);   BFLYW(3,7,W6);
    BFLY(8,12); BFLYW(9,13,W2); BFLYI(10,14); BFLYW(11,15,W6);
    BFLY(0,2);  BFLYI(1,3);  BFLY(4,6);   BFLYI(5,7);
    BFLY(8,10); BFLYI(9,11); BFLY(12,14); BFLYI(13,15);
    BFLY(0,1); BFLY(2,3); BFLY(4,5); BFLY(6,7);
    BFLY(8,9); BFLY(10,11); BFLY(12,13); BFLY(14,15);
    CSWAP(1,8); CSWAP(2,4); CSWAP(3,12); CSWAP(5,10); CSWAP(7,14); CSWAP(11,13);
}

// physical LDS index (float2 units), XOR-swizzled exact-stride layouts.
// Round 1: logical (row k1<16, col t<256): bank set = low4 of (col^row).
// Round 2: logical (row t<256, col k2<16): bank set = low4 of (col^row).
// All wave accesses hit 16 distinct bank-pair slots x 4 lanes = the 4-beat
// minimum for 8B/lane (same as the old 272/17 padded layouts, at 32KiB total).
__device__ __forceinline__ int ph1(int row, int col) { return row * 256 + (col ^ row); }
__device__ __forceinline__ int ph2(int row, int col) { return row * 16 + (col ^ (row & 15)); }

__device__ __forceinline__ void fft4096_fwd(float2* x, float2* lds, int t) {
    float2 w[16];
    #pragma unroll
    for (int k = 1; k < 16; ++k) w[k] = d_Tw1[t * 16 + k];
    dft16<-1, true>(x);
    #pragma unroll
    for (int k = 1; k < 16; ++k) x[k] = cmul(x[k], w[k]);
    #pragma unroll
    for (int k1 = 0; k1 < 16; ++k1) lds[ph1(k1, t)] = x[k1];
    __syncthreads();
    const int hi = t >> 4, lo = t & 15;
    #pragma unroll
    for (int t1 = 0; t1 < 16; ++t1) x[t1] = lds[ph1(hi, t1 * 16 + lo)];
    #pragma unroll
    for (int k = 1; k < 16; ++k) w[k] = d_Tw2[lo * 16 + k];
    dft16<-1, false>(x);
    #pragma unroll
    for (int k = 1; k < 16; ++k) x[k] = cmul(x[k], w[k]);
    __syncthreads();
    #pragma unroll
    for (int k2 = 0; k2 < 16; ++k2) lds[ph2(t, k2)] = x[k2];
    __syncthreads();
    #pragma unroll
    for (int t0 = 0; t0 < 16; ++t0) x[t0] = lds[ph2(hi * 16 + t0, lo)];
    dft16<-1, false>(x);
}

__device__ __forceinline__ void fft4096_inv(float2* x, float2* lds, int t) {
    const int hi = t >> 4, lo = t & 15;
    float2 w[16];
    dft16<1, false>(x);
    __syncthreads();
    #pragma unroll
    for (int t0 = 0; t0 < 16; ++t0) lds[ph2(hi * 16 + t0, lo)] = x[t0];
    #pragma unroll
    for (int k = 1; k < 16; ++k) w[k] = d_Tw2[lo * 16 + k];
    __syncthreads();
    #pragma unroll
    for (int k2 = 0; k2 < 16; ++k2) x[k2] = lds[ph2(t, k2)];
    #pragma unroll
    for (int k = 1; k < 16; ++k) x[k] = cmulc(x[k], w[k]);
    dft16<1, false>(x);
    __syncthreads();
    #pragma unroll
    for (int t1 = 0; t1 < 16; ++t1) lds[ph1(hi, t1 * 16 + lo)] = x[t1];
    #pragma unroll
    for (int k = 1; k < 16; ++k) w[k] = d_Tw1[t * 16 + k];
    __syncthreads();
    #pragma unroll
    for (int k1 = 0; k1 < 16; ++k1) x[k1] = lds[ph1(k1, t)];
    #pragma unroll
    for (int k = 1; k < 16; ++k) x[k] = cmulc(x[k], w[k]);
    dft16<1, false>(x);
}

// ------------------------------- filter MLP --------------------------------
// 512 blocks x 4 rows: 2 blocks/CU (2 waves/SIMD) to hide the serial q-loop
// latency (was 256 blocks = 1 wave/SIMD).
__global__ __launch_bounds__(256) void filter_k_kernel(
    const float* __restrict__ z, const float* __restrict__ sf,
    const float* __restrict__ eo, const float* __restrict__ eo_b,
    const float* __restrict__ oo1, const float* __restrict__ oo1_b,
    const float* __restrict__ oo2, const float* __restrict__ oo2_b,
    const float* __restrict__ oh, float* __restrict__ kfil)
{
    __shared__ float h3buf[4][128];
    __shared__ float htmp[2][128];
    const int t = threadIdx.x;
    const int l0 = blockIdx.x * 4;
    const int half = t >> 7;
    const int o = t & 127;
    const float sfo = sf[o];
    for (int p = 0; p < 2; ++p) {
        const int li = p * 2 + half;
        const int l = l0 + li;
        float a = eo_b[o];
        #pragma unroll
        for (int e = 0; e < 5; ++e) a += z[l * 5 + e] * eo[e * 128 + o];
        htmp[half][o] = sinf(sfo * a);
        __syncthreads();
        float a2 = oo1_b[o];
        for (int q = 0; q < 128; ++q) a2 += htmp[half][q] * oo1[q * 128 + o];
        const float h2 = sinf(sfo * a2);
        __syncthreads();
        htmp[half][o] = h2;
        __syncthreads();
        float a3 = oo2_b[o];
        for (int q = 0; q < 128; ++q) a3 += htmp[half][q] * oo2[q * 128 + o];
        h3buf[li][o] = sinf(sfo * a3);
        __syncthreads();
    }
    const float MIND = -3.070113457325394f;
    const float MAXD = -15.350567286626972f;
    for (int c = 0; c < 3; ++c) {
        const int h = t + c * 256;
        float acc[4];
        #pragma unroll
        for (int li = 0; li < 4; ++li) acc[li] = 0.f;
        for (int q = 0; q < 128; ++q) {
            const float w = oh[q * 768 + h];
            #pragma unroll
            for (int li = 0; li < 4; ++li) acc[li] += h3buf[li][q] * w;
        }
        const float delta = fabsf(MIND + (MAXD - MIND) * (float)h * (1.0f / 767.0f));
        #pragma unroll
        for (int li = 0; li < 4; ++li) {
            const int l = l0 + li;
            const float tt = (float)l * (1.0f / 2047.0f);
            kfil[h * 2048 + l] = acc[li] * expf(-tt * delta);
        }
    }
}

// --------------------------- filter FFT ------------------------------------
// Stores Kf pre-scaled by 1/4096 (irfft normalization folded in).
__global__ __launch_bounds__(256, 5) void filter_fft_kernel(
    const float* __restrict__ kfil, float2* __restrict__ Kf)
{
    __shared__ __align__(16) float2 lds[4096];
    const int d = blockIdx.x, t = threadIdx.x;
    float2 x[16];
    #pragma unroll
    for (int r = 0; r < 8; ++r) x[r] = make_float2(kfil[d * 2048 + r * 256 + t], 0.f);
    fft4096_fwd(x, lds, t);
    const float s = 1.0f / 4096.0f;
    #pragma unroll
    for (int k3 = 0; k3 < 16; ++k3)
        Kf[d * 4096 + k3 * 256 + t] = make_float2(x[k3].x * s, x[k3].y * s);
}

// --------------------------- conversions/transposes ------------------------
__global__ __launch_bounds__(256) void convert_u_kernel(
    const float* __restrict__ u, unsigned short* __restrict__ ub)
{
    const int g = blockIdx.x * 256 + threadIdx.x;
    const float4 v = ((const float4*)u)[g];
    uint2 o;
    o.x = (unsigned)f2b(v.x) | ((unsigned)f2b(v.y) << 16);
    o.y = (unsigned)f2b(v.z) | ((unsigned)f2b(v.w) << 16);
    ((uint2*)ub)[g] = o;
}

__global__ __launch_bounds__(256) void transpose_W_kernel(
    const float* __restrict__ W, unsigned short* __restrict__ Wt, int K, int N)
{
    __shared__ float tile[32][33];
    const int n0 = blockIdx.x * 32, k0 = blockIdx.y * 32;
    const int tx = threadIdx.x & 31, ty = threadIdx.x >> 5;
    #pragma unroll
    for (int r = 0; r < 4; ++r) {
        const int kk = ty + r * 8;
        tile[kk][tx] = W[(k0 + kk) * N + n0 + tx];
    }
    __syncthreads();
    #pragma unroll
    for (int r = 0; r < 4; ++r) {
        const int nn = ty + r * 8;
        Wt[(n0 + nn) * K + k0 + tx] = f2b(tile[tx][nn]);
    }
}

__global__ __launch_bounds__(256) void transpose_Y_kernel(
    const unsigned short* __restrict__ Y, unsigned short* __restrict__ Yt)
{
    __shared__ unsigned short tile[32][34];
    const int bx = blockIdx.x;
    const int l0 = (bx & 63) * 32;
    const int tmp = bx >> 6;
    const int d0 = (tmp % 24) * 32;
    const int b  = tmp / 24;
    const int tx = threadIdx.x & 31, ty = threadIdx.x >> 5;
    #pragma unroll
    for (int r = 0; r < 4; ++r) {
        const int dd = ty + r * 8;
        tile[dd][tx] = Y[(b * 768 + d0 + dd) * 2048 + l0 + tx];
    }
    __syncthreads();
    #pragma unroll
    for (int r = 0; r < 4; ++r) {
        const int ll = ty + r * 8;
        Yt[(b * 2048 + l0 + ll) * 768 + d0 + tx] = tile[tx][ll];
    }
}

// ------------------------------- bf16 GEMM ---------------------------------
// 256x256 tile, BK=64, 8 waves (2Mx4N), wave tile 128x64, 8-phase schedule.
// (unchanged from R8 — see that round's header for the stage/fence proof)
__global__ __launch_bounds__(512, 2) void gemm256_kernel(
    const unsigned short* __restrict__ A,
    const unsigned short* __restrict__ Bm,
    const float* __restrict__ bias,
    unsigned short* __restrict__ outb,
    float* __restrict__ outf,
    int mode)
{
    extern __shared__ __align__(16) unsigned short lds[];
    unsigned short* As = lds;            // [2][256][64]  2*32 KiB
    unsigned short* Bs = lds + 32768;    // [2][256][64]  2*32 KiB
    const int t = threadIdx.x;
    const int wv = t >> 6, lane = t & 63;
    const int row0 = (mode == 0 ? blockIdx.y : blockIdx.x) * 256;
    const int col0 = (mode == 0 ? blockIdx.x : blockIdx.y) * 256;
    const int wr = wv >> 2, wc = wv & 3;
    const int frow = lane & 15, kc = lane >> 4;

    f32x4 acc[8][4] = {};

    const int srow = t >> 3;
    const int cdat = (t & 7) ^ (srow & 7);
    const unsigned short* gA = A  + (row0 + srow) * 768 + cdat * 8;
    const unsigned short* gB = Bm + (col0 + srow) * 768 + cdat * 8;

#define STG_A(buf, q, koff) GLD16(gA + (q) * 49152 + (koff), (char*)As + (buf) * 32768 + (q) * 8192 + wv * 1024)
#define STG_B(buf, q, koff) GLD16(gB + (q) * 49152 + (koff), (char*)Bs + (buf) * 32768 + (q) * 8192 + wv * 1024)

    const int sx = frow & 7;
    const int aRowBase = (wr * 128 + frow) * 64;
    const int bRowBase = (wc * 64 + frow) * 64;
    const int sl0 = ((0 + kc) ^ sx) * 8;   // K-sub 0
    const int sl1 = ((4 + kc) ^ sx) * 8;   // K-sub 1

    bf16x8 aF[4][2], bN0[2][2], bN1[2][2];

#define READ_A(buf, mh)                                                         \
    _Pragma("unroll") for (int m = 0; m < 4; ++m) {                             \
        aF[m][0] = *(const bf16x8*)(As + (buf) * 16384 + aRowBase + ((mh) * 4 + m) * 1024 + sl0); \
        aF[m][1] = *(const bf16x8*)(As + (buf) * 16384 + aRowBase + ((mh) * 4 + m) * 1024 + sl1); \
    }
#define READ_B(buf, nh, arr)                                                    \
    _Pragma("unroll") for (int n = 0; n < 2; ++n) {                             \
        arr[n][0] = *(const bf16x8*)(Bs + (buf) * 16384 + bRowBase + ((nh) * 2 + n) * 1024 + sl0); \
        arr[n][1] = *(const bf16x8*)(Bs + (buf) * 16384 + bRowBase + ((nh) * 2 + n) * 1024 + sl1); \
    }
#define MFMA_Q(mh, nh, arr)                                                     \
    __builtin_amdgcn_s_setprio(1);                                              \
    _Pragma("unroll") for (int m = 0; m < 4; ++m)                               \
    _Pragma("unroll") for (int n = 0; n < 2; ++n)                               \
    _Pragma("unroll") for (int ks = 0; ks < 2; ++ks)                            \
        acc[(mh) * 4 + m][(nh) * 2 + n] = __builtin_amdgcn_mfma_f32_16x16x32_bf16( \
            aF[m][ks], arr[n][ks], acc[(mh) * 4 + m][(nh) * 2 + n], 0, 0, 0);   \
    __builtin_amdgcn_s_setprio(0);

    // prologue: tile 0 complete (8 issues, oldest) + tile 1 minus Aq1/Aq3
    STG_A(0, 0, 0); STG_A(0, 1, 0); STG_A(0, 2, 0); STG_A(0, 3, 0);
    STG_B(0, 0, 0); STG_B(0, 1, 0); STG_B(0, 2, 0); STG_B(0, 3, 0);
    STG_A(1, 0, 64); STG_A(1, 2, 64);
    STG_B(1, 0, 64); STG_B(1, 1, 64); STG_B(1, 2, 64); STG_B(1, 3, 64);
    VM_LGKM_BAR(6);   // forces the oldest 8 (= tile 0) landed

    for (int i = 0; i < 5; ++i) {
        const int k1 = (2 * i + 1) * 64, k2 = (2 * i + 2) * 64, k3 = (2 * i + 3) * 64;
        // P1: Qa(buf0)
        READ_A(0, 0); READ_B(0, 0, bN0);
        STG_A(1, 1, k1); STG_A(1, 3, k1);
        MFMA_Q(0, 0, bN0);
        LGKM_BAR;
        // P2: Qb(buf0)
        READ_B(0, 1, bN1);
        STG_A(0, 0, k2); STG_A(0, 2, k2);
        MFMA_Q(0, 1, bN1);
        LGKM_BAR;
        // P3: Qc(buf0)
        READ_A(0, 1);
        STG_B(0, 0, k2); STG_B(0, 1, k2);
        MFMA_Q(1, 1, bN1);
        LGKM_BAR;
        // P4: Qd(buf0) — register reuse only
        STG_B(0, 2, k2); STG_B(0, 3, k2);
        MFMA_Q(1, 0, bN0);
        VM_LGKM_BAR(6);
        // P5: Qa(buf1)
        READ_A(1, 0); READ_B(1, 0, bN0);
        STG_A(0, 1, k2); STG_A(0, 3, k2);
        MFMA_Q(0, 0, bN0);
        LGKM_BAR;
        // P6: Qb(buf1)
        READ_B(1, 1, bN1);
        STG_A(1, 0, k3); STG_A(1, 2, k3);
        MFMA_Q(0, 1, bN1);
        LGKM_BAR;
        // P7: Qc(buf1)
        READ_A(1, 1);
        STG_B(1, 0, k3); STG_B(1, 1, k3);
        MFMA_Q(1, 1, bN1);
        LGKM_BAR;
        // P8: Qd(buf1)
        STG_B(1, 2, k3); STG_B(1, 3, k3);
        MFMA_Q(1, 0, bN0);
        VM_LGKM_BAR(6);
    }

    // epilogue: tiles 10 (buf0) and 11 (buf1); only P1's stage remains
    {
        // P1
        READ_A(0, 0); READ_B(0, 0, bN0);
        STG_A(1, 1, 704); STG_A(1, 3, 704);   // tile 11 tail
        MFMA_Q(0, 0, bN0);
        LGKM_BAR;
        // P2
        READ_B(0, 1, bN1);
        MFMA_Q(0, 1, bN1);
        LGKM_BAR;
        // P3
        READ_A(0, 1);
        MFMA_Q(1, 1, bN1);
        LGKM_BAR;
        // P4 — forces tile 11 body (i4 P6..P8 issues) landed
        MFMA_Q(1, 0, bN0);
        VM_LGKM_BAR(2);
        // P5
        READ_A(1, 0); READ_B(1, 0, bN0);
        MFMA_Q(0, 0, bN0);
        LGKM_BAR;
        // P6 — forces tile 11 Aq1/Aq3 landed; vmcnt==0 from here on
        READ_B(1, 1, bN1);
        MFMA_Q(0, 1, bN1);
        VM_LGKM_BAR(0);
        // P7
        READ_A(1, 1);
        MFMA_Q(1, 1, bN1);
        // P8
        MFMA_Q(1, 0, bN0);
    }
#undef READ_A
#undef READ_B
#undef MFMA_Q
#undef STG_A
#undef STG_B

    if (mode == 0) {
        const int part = row0 / 768;        // 768 % 256 == 0: uniform per block
        const int bb = col0 / 2048;         // 2048 % 256 == 0: uniform per block
        unsigned short* Xp = outb + (size_t)(part * 8 + bb) * 768 * 2048;
        const int drow0 = row0 - part * 768 + wr * 128 + (lane >> 4) * 4;
        const int lcol0 = col0 - bb * 2048 + wc * 64 + frow;
        #pragma unroll
        for (int m = 0; m < 8; ++m) {
            #pragma unroll
            for (int rr = 0; rr < 4; ++rr) {
                const int dd = drow0 + m * 16 + rr;
                const float bn = bias[row0 + wr * 128 + (lane >> 4) * 4 + m * 16 + rr];
                #pragma unroll
                for (int n = 0; n < 4; ++n)
                    Xp[dd * 2048 + lcol0 + n * 16] = f2b(acc[m][n][rr] + bn);
            }
        }
    } else {
        #pragma unroll
        for (int m = 0; m < 8; ++m) {
            #pragma unroll
            for (int rr = 0; rr < 4; ++rr) {
                const int mm = row0 + wr * 128 + (lane >> 4) * 4 + m * 16 + rr;
                #pragma unroll
                for (int n = 0; n < 4; ++n) {
                    const int nn = col0 + wc * 64 + n * 16 + frow;
                    outf[(size_t)mm * 768 + nn] = acc[m][n][rr] + bias[nn];
                }
            }
        }
    }
}

// --------------------- fused conv4 + gate + FFT conv -----------------------
__device__ __forceinline__ void conv6(const unsigned short* __restrict__ p,
                                      const float* w, float bias, int t, float* out8)
{
    const uint4 m = *(const uint4*)(p + 8 * t);
    uint2 q = make_uint2(0u, 0u);
    if (t) q = *(const uint2*)(p + 8 * t - 4);
    float s[12];
    s[0] = b2f_lo(q.x); s[1] = b2f_hi(q.x); s[2] = b2f_lo(q.y); s[3] = b2f_hi(q.y);
    s[4] = b2f_lo(m.x); s[5] = b2f_hi(m.x); s[6] = b2f_lo(m.y); s[7] = b2f_hi(m.y);
    s[8] = b2f_lo(m.z); s[9] = b2f_hi(m.z); s[10] = b2f_lo(m.w); s[11] = b2f_hi(m.w);
    #pragma unroll
    for (int i = 0; i < 8; ++i)
        out8[i] = bias + w[0] * s[i + 1] + w[1] * s[i + 2] + w[2] * s[i + 3] + w[3] * s[i + 4];
}

// grid (768, 4): x=d (same-d blocks 768 apart -> same XCD -> Kf L2 reuse)
__global__ __launch_bounds__(256, 5) void fft_conv_kernel(
    const unsigned short* __restrict__ X, const float2* __restrict__ Kf,
    const float* __restrict__ x1_s, const float* __restrict__ x2_s, const float* __restrict__ v_s,
    const float* __restrict__ x1_sb, const float* __restrict__ x2_sb, const float* __restrict__ v_sb,
    const float* __restrict__ D_bias, unsigned short* __restrict__ Y)
{
    __shared__ __align__(16) float2 lds[4096];
    unsigned* ldsu = (unsigned*)lds;
    const int d = blockIdx.x, jp = blockIdx.y, t = threadIdx.x;
    const int b0 = jp * 2, b1 = b0 + 1;

    float w1[4], w2[4], wv[4];
    #pragma unroll
    for (int j = 0; j < 4; ++j) { w1[j] = x1_s[d * 4 + j]; w2[j] = x2_s[d * 4 + j]; wv[j] = v_s[d * 4 + j]; }
    const float bc1 = x1_sb[d], bc2 = x2_sb[d], bcv = v_sb[d], Db = D_bias[d];

    const unsigned short* px1a = X + ((size_t)(0 * 8 + b0) * 768 + d) * 2048;
    const unsigned short* px2a = X + ((size_t)(1 * 8 + b0) * 768 + d) * 2048;
    const unsigned short* pva  = X + ((size_t)(2 * 8 + b0) * 768 + d) * 2048;
    const unsigned short* px1b = X + ((size_t)(0 * 8 + b1) * 768 + d) * 2048;
    const unsigned short* px2b = X + ((size_t)(1 * 8 + b1) * 768 + d) * 2048;
    const unsigned short* pvb  = X + ((size_t)(2 * 8 + b1) * 768 + d) * 2048;

    {
        float x1a[8], x2a[8], vva[8];
        conv6(px1a, w1, bc1, t, x1a);
        conv6(px2a, w2, bc2, t, x2a);
        conv6(pva,  wv, bcv, t, vva);
        float x1b[8], x2b[8], vvb[8];
        conv6(px1b, w1, bc1, t, x1b);
        conv6(px2b, w2, bc2, t, x2b);
        conv6(pvb,  wv, bcv, t, vvb);
        unsigned vh_pk[8], c2_pk[8];
        #pragma unroll
        for (int i = 0; i < 8; ++i) {
            vh_pk[i] = (unsigned)f2b(vva[i] * x1a[i]) | ((unsigned)f2b(vvb[i] * x1b[i]) << 16);
            c2_pk[i] = (unsigned)f2b(x2a[i]) | ((unsigned)f2b(x2b[i]) << 16);
        }
        *(uint4*)(ldsu + 8 * t)        = make_uint4(vh_pk[0], vh_pk[1], vh_pk[2], vh_pk[3]);
        *(uint4*)(ldsu + 8 * t + 4)    = make_uint4(vh_pk[4], vh_pk[5], vh_pk[6], vh_pk[7]);
        *(uint4*)(ldsu + 2048 + 8 * t)     = make_uint4(c2_pk[0], c2_pk[1], c2_pk[2], c2_pk[3]);
        *(uint4*)(ldsu + 2048 + 8 * t + 4) = make_uint4(c2_pk[4], c2_pk[5], c2_pk[6], c2_pk[7]);
    }
    __syncthreads();

    unsigned vhp[8], c2p[8];
    float2 x[16];
    #pragma unroll
    for (int r = 0; r < 8; ++r) {
        const unsigned u = ldsu[r * 256 + t];
        vhp[r] = u;
        x[r] = make_float2(b2f_lo(u), b2f_hi(u));
    }
    #pragma unroll
    for (int r = 0; r < 8; ++r) c2p[r] = ldsu[2048 + r * 256 + t];

    const float2* kf = Kf + (size_t)d * 4096;
    float2 kfr[16];
    #pragma unroll
    for (int k3 = 0; k3 < 16; ++k3) kfr[k3] = kf[k3 * 256 + t];

    __syncthreads();

    fft4096_fwd(x, lds, t);
    #pragma unroll
    for (int k3 = 0; k3 < 16; ++k3) x[k3] = cmul(x[k3], kfr[k3]);
    fft4096_inv(x, lds, t);

    // Kf pre-scaled by 1/4096: x already carries irfft normalization.
    unsigned short* ya = Y + ((size_t)b0 * 768 + d) * 2048;
    unsigned short* yb = Y + ((size_t)b1 * 768 + d) * 2048;
    #pragma unroll
    for (int n1 = 0; n1 < 8; ++n1) {
        const int l = n1 * 256 + t;
        const float va = b2f_lo(vhp[n1]);
        const float vb = b2f_hi(vhp[n1]);
        const float ca = b2f_lo(c2p[n1]);
        const float cb = b2f_hi(c2p[n1]);
        ya[l] = f2b((x[n1].x + va * Db) * ca);
        yb[l] = f2b((x[n1].y + vb * Db) * cb);
    }
}

// --------------------------------- launch ----------------------------------
extern "C" void kernel_launch(void* const* d_in, const int* in_sizes, int n_in,
                              void* d_out, int out_size, void* d_ws, size_t ws_size,
                              hipStream_t stream)
{
    (void)in_sizes; (void)n_in; (void)out_size; (void)ws_size;
    const float* u      = (const float*)d_in[0];
    const float* in_W   = (const float*)d_in[1];
    const float* in_b   = (const float*)d_in[2];
    const float* out_W  = (const float*)d_in[3];
    const float* out_b  = (const float*)d_in[4];
    const float* x1_s   = (const float*)d_in[5];
    const float* x2_s   = (const float*)d_in[6];
    const float* v_s    = (const float*)d_in[7];
    const float* x1_sb  = (const float*)d_in[8];
    const float* x2_sb  = (const float*)d_in[9];
    const float* v_sb   = (const float*)d_in[10];
    const float* D_bias = (const float*)d_in[11];
    const float* z      = (const float*)d_in[12];
    const float* sf     = (const float*)d_in[13];
    const float* eo     = (const float*)d_in[14];
    const float* eo_b   = (const float*)d_in[15];
    const float* oo1    = (const float*)d_in[16];
    const float* oo1_b  = (const float*)d_in[17];
    const float* oo2    = (const float*)d_in[18];
    const float* oo2_b  = (const float*)d_in[19];
    const float* oh     = (const float*)d_in[20];
    float* out = (float*)d_out;

    char* ws = (char*)d_ws;
    unsigned short* Xbf  = (unsigned short*)(ws + 0);          //  75,497,472 X[3][8][768][2048] bf16
    unsigned short* Ybf  = (unsigned short*)(ws + 75497472);   //  25,165,824 Y[8][768][2048] bf16
    unsigned short* ubYt = (unsigned short*)(ws + 100663296);  //  25,165,824 ub, later aliased as Yt
    unsigned short* Wt   = (unsigned short*)(ws + 125829120);  //   3,538,944 Wt[2304][768] bf16
    unsigned short* W2t  = (unsigned short*)(ws + 129368064);  //   1,179,648 W2t[768][768] bf16
    float*          kfil = (float*)(ws + 130547712);           //   6,291,456 k[768][2048] fp32
    float2*         Kf   = (float2*)(ws + 136839168);          //  25,165,824 K_f[768][16][256] cplx (permuted, pre-scaled 1/4096)

    static int attr_set = 0;
    if (!attr_set) {
        (void)hipFuncSetAttribute(reinterpret_cast<const void*>(gemm256_kernel),
                                  hipFuncAttributeMaxDynamicSharedMemorySize, 131072);
        attr_set = 1;
    }

    twiddle_init_kernel<<<17, 256, 0, stream>>>();
    filter_k_kernel<<<512, 256, 0, stream>>>(z, sf, eo, eo_b, oo1, oo1_b, oo2, oo2_b, oh, kfil);
    filter_fft_kernel<<<768, 256, 0, stream>>>(kfil, Kf);
    convert_u_kernel<<<12288, 256, 0, stream>>>(u, ubYt);
    transpose_W_kernel<<<dim3(72, 24), 256, 0, stream>>>(in_W, Wt, 768, 2304);
    transpose_W_kernel<<<dim3(24, 24), 256, 0, stream>>>(out_W, W2t, 768, 768);
    gemm256_kernel<<<dim3(64, 9), 512, 131072, stream>>>(Wt, ubYt, in_b, Xbf, nullptr, 0);
    fft_conv_kernel<<<dim3(768, 4), 256, 0, stream>>>(Xbf, Kf, x1_s, x2_s, v_s, x1_sb, x2_sb, v_sb, D_bias, Ybf);
    transpose_Y_kernel<<<12288, 256, 0, stream>>>(Ybf, ubYt);
    gemm256_kernel<<<dim3(64, 3), 512, 131072, stream>>>(ubYt, W2t, out_b, nullptr, out, 1);
}

// Round 3
// 428.415 us; speedup vs baseline: 1.1598x; 1.1598x over previous
//
#include <hip/hip_runtime.h>

// ---------------------------------------------------------------------------
// FlashMMSequenceMixing (Hyena-style): B=8, L=2048, D=768, ORDER=128, FFT=4096
// R9 -> R10: fix the R9 regression (fft_conv 91->199us). Root cause from
// counters: VGPR_Count 48 + FETCH/WRITE tripled = scratch spills. The fft
// working set is ~100 VGPRs; launch_bounds' 2nd arg only sets a MIN waves/EU,
// so the allocator chased 8 waves/SIMD and spilled.
//  1) fft_conv / filter_fft: __attribute__((amdgpu_waves_per_eu(4,N))) pins
//     the occupancy target -> full 128-VGPR budget, no spills.
//  2) kfr (16 x float2) no longer preloaded across the forward FFT: loaded
//     from global right before the pointwise multiply (Kf is L2-resident
//     per-XCD; one ~200cyc round hidden by 16 resident waves). Frees 32 VGPRs
//     at the pressure peak.
//  Kept from R9: 32KiB XOR-swizzled FFT LDS, twiddle tables, 1/4096 folded
//  into Kf, filter_k 512x4. GEMM unchanged.
// ---------------------------------------------------------------------------

typedef __bf16 bf16x8 __attribute__((ext_vector_type(8)));
typedef float  f32x4  __attribute__((ext_vector_type(4)));

#define AS1 __attribute__((address_space(1)))
#define AS3 __attribute__((address_space(3)))
#define GLD16(gp, lp) __builtin_amdgcn_global_load_lds((AS1 void*)(void*)(gp), (AS3 void*)(void*)(lp), 16, 0, 0)

// compiler-visible fences (memory clobber pins LDS/global ops to program order)
#define LGKM_BAR       __asm__ __volatile__("s_waitcnt lgkmcnt(0)\n\ts_barrier" ::: "memory")
#define VM_LGKM_BAR(N) __asm__ __volatile__("s_waitcnt vmcnt(" #N ") lgkmcnt(0)\n\ts_barrier" ::: "memory")

__device__ __forceinline__ unsigned short f2b(float f) {
    unsigned u = __builtin_bit_cast(unsigned, f);
    unsigned r = (u + 0x7fffu + ((u >> 16) & 1u)) >> 16;
    return (unsigned short)r;
}
__device__ __forceinline__ float b2f(unsigned short h) {
    unsigned u = ((unsigned)h) << 16;
    return __builtin_bit_cast(float, u);
}
__device__ __forceinline__ float b2f_lo(unsigned u) {
    return __builtin_bit_cast(float, u << 16);
}
__device__ __forceinline__ float b2f_hi(unsigned u) {
    return __builtin_bit_cast(float, u & 0xffff0000u);
}

__device__ __forceinline__ float2 cmul(float2 a, float2 b) {
    return make_float2(a.x * b.x - a.y * b.y, a.x * b.y + a.y * b.x);
}
__device__ __forceinline__ float2 cmulc(float2 a, float2 b) {  // a * conj(b)
    return make_float2(a.x * b.x + a.y * b.y, a.y * b.x - a.x * b.y);
}
__device__ __forceinline__ float2 cadd(float2 a, float2 b) { return make_float2(a.x + b.x, a.y + b.y); }
__device__ __forceinline__ float2 csub(float2 a, float2 b) { return make_float2(a.x - b.x, a.y - b.y); }

// ------------------------- twiddle tables ----------------------------------
#define TWO_PI 6.283185307179586f
__device__ float2 d_Tw1[4096];   // [t][k] = exp(-i 2pi t k / 4096), t<256, k<16
__device__ float2 d_Tw2[256];    // [lo][k] = exp(-i 2pi lo k / 256), lo<16, k<16

__global__ __launch_bounds__(256) void twiddle_init_kernel() {
    const int i = blockIdx.x * 256 + threadIdx.x;   // grid 17*256 = 4352
    if (i < 4096) {
        const int tt = i >> 4, k = i & 15;
        float s, c;
        __sincosf(-(float)(tt * k) * (TWO_PI / 4096.0f), &s, &c);
        d_Tw1[i] = make_float2(c, s);
    } else {
        const int j = i - 4096;
        const int lo = j >> 4, k = j & 15;
        float s, c;
        __sincosf(-(float)(lo * k) * (TWO_PI / 256.0f), &s, &c);
        d_Tw2[j] = make_float2(c, s);
    }
}

// ------------------------- 16-point register DFT ---------------------------
#define BFLY(i,j)   { float2 ta=x[i], tb=x[j]; x[i]=cadd(ta,tb); x[j]=csub(ta,tb); }
#define BFLYW(i,j,w){ float2 ta=x[i], tb=x[j]; x[i]=cadd(ta,tb); x[j]=cmul(csub(ta,tb),(w)); }
#define BFLYI(i,j)  { float2 ta=x[i], tb=x[j]; x[i]=cadd(ta,tb); float2 tt=csub(ta,tb); x[j]=make_float2(-dd*tt.y, dd*tt.x); }
#define CSWAP(i,j)  { float2 tt=x[i]; x[i]=x[j]; x[j]=tt; }

template<int DIR, bool UZ>
__device__ __forceinline__ void dft16(float2* x) {
    const float dd = (float)DIR;
    const float C1 = 0.92387953251128674f, S1 = 0.38268343236508977f, R2 = 0.70710678118654752f;
    const float2 W1 = make_float2( C1, dd*S1);
    const float2 W2 = make_float2( R2, dd*R2);
    const float2 W3 = make_float2( S1, dd*C1);
    const float2 W5 = make_float2(-S1, dd*C1);
    const float2 W6 = make_float2(-R2, dd*R2);
    const float2 W7 = make_float2(-C1, dd*S1);
    if (UZ) {
        x[8]  = x[0];
        x[9]  = cmul(x[1], W1);
        x[10] = cmul(x[2], W2);
        x[11] = cmul(x[3], W3);
        x[12] = make_float2(-dd*x[4].y, dd*x[4].x);
        x[13] = cmul(x[5], W5);
        x[14] = cmul(x[6], W6);
        x[15] = cmul(x[7], W7);
    } else {
        BFLY(0,8); BFLYW(1,9,W1); BFLYW(2,10,W2); BFLYW(3,11,W3);
        BFLYI(4,12); BFLYW(5,13,W5); BFLYW(6,14,W6); BFLYW(7,15,W7);
    }
    BFLY(0,4);  BFLYW(1,5,W2);  BFLYI(2,6);   BFLYW(3,7,W6);
    BFLY(8,12); BFLYW(9,13,W2); BFLYI(10,14); BFLYW(11,15,W6);
    BFLY(0,2);  BFLYI(1,3);  BFLY(4,6);   BFLYI(5,7);
    BFLY(8,10); BFLYI(9,11); BFLY(12,14); BFLYI(13,15);
    BFLY(0,1); BFLY(2,3); BFLY(4,5); BFLY(6,7);
    BFLY(8,9); BFLY(10,11); BFLY(12,13); BFLY(14,15);
    CSWAP(1,8); CSWAP(2,4); CSWAP(3,12); CSWAP(5,10); CSWAP(7,14); CSWAP(11,13);
}

// physical LDS index (float2 units), XOR-swizzled exact-stride layouts.
// Round 1: logical (row k1<16, col t<256): bank set = low4 of (col^row).
// Round 2: logical (row t<256, col k2<16): bank set = low4 of (col^row).
// All wave accesses hit 16 distinct bank-pair slots x 4 lanes = the 4-beat
// minimum for 8B/lane (same as 272/17 stride padding, at 32KiB total).
__device__ __forceinline__ int ph1(int row, int col) { return row * 256 + (col ^ row); }
__device__ __forceinline__ int ph2(int row, int col) { return row * 16 + (col ^ (row & 15)); }

__device__ __forceinline__ void fft4096_fwd(float2* x, float2* lds, int t) {
    float2 w[16];
    #pragma unroll
    for (int k = 1; k < 16; ++k) w[k] = d_Tw1[t * 16 + k];
    dft16<-1, true>(x);
    #pragma unroll
    for (int k = 1; k < 16; ++k) x[k] = cmul(x[k], w[k]);
    #pragma unroll
    for (int k1 = 0; k1 < 16; ++k1) lds[ph1(k1, t)] = x[k1];
    __syncthreads();
    const int hi = t >> 4, lo = t & 15;
    #pragma unroll
    for (int t1 = 0; t1 < 16; ++t1) x[t1] = lds[ph1(hi, t1 * 16 + lo)];
    #pragma unroll
    for (int k = 1; k < 16; ++k) w[k] = d_Tw2[lo * 16 + k];
    dft16<-1, false>(x);
    #pragma unroll
    for (int k = 1; k < 16; ++k) x[k] = cmul(x[k], w[k]);
    __syncthreads();
    #pragma unroll
    for (int k2 = 0; k2 < 16; ++k2) lds[ph2(t, k2)] = x[k2];
    __syncthreads();
    #pragma unroll
    for (int t0 = 0; t0 < 16; ++t0) x[t0] = lds[ph2(hi * 16 + t0, lo)];
    dft16<-1, false>(x);
}

__device__ __forceinline__ void fft4096_inv(float2* x, float2* lds, int t) {
    const int hi = t >> 4, lo = t & 15;
    float2 w[16];
    dft16<1, false>(x);
    __syncthreads();
    #pragma unroll
    for (int t0 = 0; t0 < 16; ++t0) lds[ph2(hi * 16 + t0, lo)] = x[t0];
    #pragma unroll
    for (int k = 1; k < 16; ++k) w[k] = d_Tw2[lo * 16 + k];
    __syncthreads();
    #pragma unroll
    for (int k2 = 0; k2 < 16; ++k2) x[k2] = lds[ph2(t, k2)];
    #pragma unroll
    for (int k = 1; k < 16; ++k) x[k] = cmulc(x[k], w[k]);
    dft16<1, false>(x);
    __syncthreads();
    #pragma unroll
    for (int t1 = 0; t1 < 16; ++t1) lds[ph1(hi, t1 * 16 + lo)] = x[t1];
    #pragma unroll
    for (int k = 1; k < 16; ++k) w[k] = d_Tw1[t * 16 + k];
    __syncthreads();
    #pragma unroll
    for (int k1 = 0; k1 < 16; ++k1) x[k1] = lds[ph1(k1, t)];
    #pragma unroll
    for (int k = 1; k < 16; ++k) x[k] = cmulc(x[k], w[k]);
    dft16<1, false>(x);
}

// ------------------------------- filter MLP --------------------------------
// 512 blocks x 4 rows: 2 blocks/CU (2 waves/SIMD) to hide the serial q-loop
// latency.
__global__ __launch_bounds__(256) void filter_k_kernel(
    const float* __restrict__ z, const float* __restrict__ sf,
    const float* __restrict__ eo, const float* __restrict__ eo_b,
    const float* __restrict__ oo1, const float* __restrict__ oo1_b,
    const float* __restrict__ oo2, const float* __restrict__ oo2_b,
    const float* __restrict__ oh, float* __restrict__ kfil)
{
    __shared__ float h3buf[4][128];
    __shared__ float htmp[2][128];
    const int t = threadIdx.x;
    const int l0 = blockIdx.x * 4;
    const int half = t >> 7;
    const int o = t & 127;
    const float sfo = sf[o];
    for (int p = 0; p < 2; ++p) {
        const int li = p * 2 + half;
        const int l = l0 + li;
        float a = eo_b[o];
        #pragma unroll
        for (int e = 0; e < 5; ++e) a += z[l * 5 + e] * eo[e * 128 + o];
        htmp[half][o] = sinf(sfo * a);
        __syncthreads();
        float a2 = oo1_b[o];
        for (int q = 0; q < 128; ++q) a2 += htmp[half][q] * oo1[q * 128 + o];
        const float h2 = sinf(sfo * a2);
        __syncthreads();
        htmp[half][o] = h2;
        __syncthreads();
        float a3 = oo2_b[o];
        for (int q = 0; q < 128; ++q) a3 += htmp[half][q] * oo2[q * 128 + o];
        h3buf[li][o] = sinf(sfo * a3);
        __syncthreads();
    }
    const float MIND = -3.070113457325394f;
    const float MAXD = -15.350567286626972f;
    for (int c = 0; c < 3; ++c) {
        const int h = t + c * 256;
        float acc[4];
        #pragma unroll
        for (int li = 0; li < 4; ++li) acc[li] = 0.f;
        for (int q = 0; q < 128; ++q) {
            const float w = oh[q * 768 + h];
            #pragma unroll
            for (int li = 0; li < 4; ++li) acc[li] += h3buf[li][q] * w;
        }
        const float delta = fabsf(MIND + (MAXD - MIND) * (float)h * (1.0f / 767.0f));
        #pragma unroll
        for (int li = 0; li < 4; ++li) {
            const int l = l0 + li;
            const float tt = (float)l * (1.0f / 2047.0f);
            kfil[h * 2048 + l] = acc[li] * expf(-tt * delta);
        }
    }
}

// --------------------------- filter FFT ------------------------------------
// Stores Kf pre-scaled by 1/4096 (irfft normalization folded in).
__global__ __launch_bounds__(256) __attribute__((amdgpu_waves_per_eu(4, 5)))
void filter_fft_kernel(
    const float* __restrict__ kfil, float2* __restrict__ Kf)
{
    __shared__ __align__(16) float2 lds[4096];
    const int d = blockIdx.x, t = threadIdx.x;
    float2 x[16];
    #pragma unroll
    for (int r = 0; r < 8; ++r) x[r] = make_float2(kfil[d * 2048 + r * 256 + t], 0.f);
    fft4096_fwd(x, lds, t);
    const float s = 1.0f / 4096.0f;
    #pragma unroll
    for (int k3 = 0; k3 < 16; ++k3)
        Kf[d * 4096 + k3 * 256 + t] = make_float2(x[k3].x * s, x[k3].y * s);
}

// --------------------------- conversions/transposes ------------------------
__global__ __launch_bounds__(256) void convert_u_kernel(
    const float* __restrict__ u, unsigned short* __restrict__ ub)
{
    const int g = blockIdx.x * 256 + threadIdx.x;
    const float4 v = ((const float4*)u)[g];
    uint2 o;
    o.x = (unsigned)f2b(v.x) | ((unsigned)f2b(v.y) << 16);
    o.y = (unsigned)f2b(v.z) | ((unsigned)f2b(v.w) << 16);
    ((uint2*)ub)[g] = o;
}

__global__ __launch_bounds__(256) void transpose_W_kernel(
    const float* __restrict__ W, unsigned short* __restrict__ Wt, int K, int N)
{
    __shared__ float tile[32][33];
    const int n0 = blockIdx.x * 32, k0 = blockIdx.y * 32;
    const int tx = threadIdx.x & 31, ty = threadIdx.x >> 5;
    #pragma unroll
    for (int r = 0; r < 4; ++r) {
        const int kk = ty + r * 8;
        tile[kk][tx] = W[(k0 + kk) * N + n0 + tx];
    }
    __syncthreads();
    #pragma unroll
    for (int r = 0; r < 4; ++r) {
        const int nn = ty + r * 8;
        Wt[(n0 + nn) * K + k0 + tx] = f2b(tile[tx][nn]);
    }
}

__global__ __launch_bounds__(256) void transpose_Y_kernel(
    const unsigned short* __restrict__ Y, unsigned short* __restrict__ Yt)
{
    __shared__ unsigned short tile[32][34];
    const int bx = blockIdx.x;
    const int l0 = (bx & 63) * 32;
    const int tmp = bx >> 6;
    const int d0 = (tmp % 24) * 32;
    const int b  = tmp / 24;
    const int tx = threadIdx.x & 31, ty = threadIdx.x >> 5;
    #pragma unroll
    for (int r = 0; r < 4; ++r) {
        const int dd = ty + r * 8;
        tile[dd][tx] = Y[(b * 768 + d0 + dd) * 2048 + l0 + tx];
    }
    __syncthreads();
    #pragma unroll
    for (int r = 0; r < 4; ++r) {
        const int ll = ty + r * 8;
        Yt[(b * 2048 + l0 + ll) * 768 + d0 + tx] = tile[tx][ll];
    }
}

// ------------------------------- bf16 GEMM ---------------------------------
// 256x256 tile, BK=64, 8 waves (2Mx4N), wave tile 128x64, 8-phase schedule.
// (unchanged from R8 — see that round's header for the stage/fence proof)
__global__ __launch_bounds__(512, 2) void gemm256_kernel(
    const unsigned short* __restrict__ A,
    const unsigned short* __restrict__ Bm,
    const float* __restrict__ bias,
    unsigned short* __restrict__ outb,
    float* __restrict__ outf,
    int mode)
{
    extern __shared__ __align__(16) unsigned short lds[];
    unsigned short* As = lds;            // [2][256][64]  2*32 KiB
    unsigned short* Bs = lds + 32768;    // [2][256][64]  2*32 KiB
    const int t = threadIdx.x;
    const int wv = t >> 6, lane = t & 63;
    const int row0 = (mode == 0 ? blockIdx.y : blockIdx.x) * 256;
    const int col0 = (mode == 0 ? blockIdx.x : blockIdx.y) * 256;
    const int wr = wv >> 2, wc = wv & 3;
    const int frow = lane & 15, kc = lane >> 4;

    f32x4 acc[8][4] = {};

    const int srow = t >> 3;
    const int cdat = (t & 7) ^ (srow & 7);
    const unsigned short* gA = A  + (row0 + srow) * 768 + cdat * 8;
    const unsigned short* gB = Bm + (col0 + srow) * 768 + cdat * 8;

#define STG_A(buf, q, koff) GLD16(gA + (q) * 49152 + (koff), (char*)As + (buf) * 32768 + (q) * 8192 + wv * 1024)
#define STG_B(buf, q, koff) GLD16(gB + (q) * 49152 + (koff), (char*)Bs + (buf) * 32768 + (q) * 8192 + wv * 1024)

    const int sx = frow & 7;
    const int aRowBase = (wr * 128 + frow) * 64;
    const int bRowBase = (wc * 64 + frow) * 64;
    const int sl0 = ((0 + kc) ^ sx) * 8;   // K-sub 0
    const int sl1 = ((4 + kc) ^ sx) * 8;   // K-sub 1

    bf16x8 aF[4][2], bN0[2][2], bN1[2][2];

#define READ_A(buf, mh)                                                         \
    _Pragma("unroll") for (int m = 0; m < 4; ++m) {                             \
        aF[m][0] = *(const bf16x8*)(As + (buf) * 16384 + aRowBase + ((mh) * 4 + m) * 1024 + sl0); \
        aF[m][1] = *(const bf16x8*)(As + (buf) * 16384 + aRowBase + ((mh) * 4 + m) * 1024 + sl1); \
    }
#define READ_B(buf, nh, arr)                                                    \
    _Pragma("unroll") for (int n = 0; n < 2; ++n) {                             \
        arr[n][0] = *(const bf16x8*)(Bs + (buf) * 16384 + bRowBase + ((nh) * 2 + n) * 1024 + sl0); \
        arr[n][1] = *(const bf16x8*)(Bs + (buf) * 16384 + bRowBase + ((nh) * 2 + n) * 1024 + sl1); \
    }
#define MFMA_Q(mh, nh, arr)                                                     \
    __builtin_amdgcn_s_setprio(1);                                              \
    _Pragma("unroll") for (int m = 0; m < 4; ++m)                               \
    _Pragma("unroll") for (int n = 0; n < 2; ++n)                               \
    _Pragma("unroll") for (int ks = 0; ks < 2; ++ks)                            \
        acc[(mh) * 4 + m][(nh) * 2 + n] = __builtin_amdgcn_mfma_f32_16x16x32_bf16( \
            aF[m][ks], arr[n][ks], acc[(mh) * 4 + m][(nh) * 2 + n], 0, 0, 0);   \
    __builtin_amdgcn_s_setprio(0);

    // prologue: tile 0 complete (8 issues, oldest) + tile 1 minus Aq1/Aq3
    STG_A(0, 0, 0); STG_A(0, 1, 0); STG_A(0, 2, 0); STG_A(0, 3, 0);
    STG_B(0, 0, 0); STG_B(0, 1, 0); STG_B(0, 2, 0); STG_B(0, 3, 0);
    STG_A(1, 0, 64); STG_A(1, 2, 64);
    STG_B(1, 0, 64); STG_B(1, 1, 64); STG_B(1, 2, 64); STG_B(1, 3, 64);
    VM_LGKM_BAR(6);   // forces the oldest 8 (= tile 0) landed

    for (int i = 0; i < 5; ++i) {
        const int k1 = (2 * i + 1) * 64, k2 = (2 * i + 2) * 64, k3 = (2 * i + 3) * 64;
        // P1: Qa(buf0)
        READ_A(0, 0); READ_B(0, 0, bN0);
        STG_A(1, 1, k1); STG_A(1, 3, k1);
        MFMA_Q(0, 0, bN0);
        LGKM_BAR;
        // P2: Qb(buf0)
        READ_B(0, 1, bN1);
        STG_A(0, 0, k2); STG_A(0, 2, k2);
        MFMA_Q(0, 1, bN1);
        LGKM_BAR;
        // P3: Qc(buf0)
        READ_A(0, 1);
        STG_B(0, 0, k2); STG_B(0, 1, k2);
        MFMA_Q(1, 1, bN1);
        LGKM_BAR;
        // P4: Qd(buf0) — register reuse only
        STG_B(0, 2, k2); STG_B(0, 3, k2);
        MFMA_Q(1, 0, bN0);
        VM_LGKM_BAR(6);
        // P5: Qa(buf1)
        READ_A(1, 0); READ_B(1, 0, bN0);
        STG_A(0, 1, k2); STG_A(0, 3, k2);
        MFMA_Q(0, 0, bN0);
        LGKM_BAR;
        // P6: Qb(buf1)
        READ_B(1, 1, bN1);
        STG_A(1, 0, k3); STG_A(1, 2, k3);
        MFMA_Q(0, 1, bN1);
        LGKM_BAR;
        // P7: Qc(buf1)
        READ_A(1, 1);
        STG_B(1, 0, k3); STG_B(1, 1, k3);
        MFMA_Q(1, 1, bN1);
        LGKM_BAR;
        // P8: Qd(buf1)
        STG_B(1, 2, k3); STG_B(1, 3, k3);
        MFMA_Q(1, 0, bN0);
        VM_LGKM_BAR(6);
    }

    // epilogue: tiles 10 (buf0) and 11 (buf1); only P1's stage remains
    {
        // P1
        READ_A(0, 0); READ_B(0, 0, bN0);
        STG_A(1, 1, 704); STG_A(1, 3, 704);   // tile 11 tail
        MFMA_Q(0, 0, bN0);
        LGKM_BAR;
        // P2
        READ_B(0, 1, bN1);
        MFMA_Q(0, 1, bN1);
        LGKM_BAR;
        // P3
        READ_A(0, 1);
        MFMA_Q(1, 1, bN1);
        LGKM_BAR;
        // P4 — forces tile 11 body (i4 P6..P8 issues) landed
        MFMA_Q(1, 0, bN0);
        VM_LGKM_BAR(2);
        // P5
        READ_A(1, 0); READ_B(1, 0, bN0);
        MFMA_Q(0, 0, bN0);
        LGKM_BAR;
        // P6 — forces tile 11 Aq1/Aq3 landed; vmcnt==0 from here on
        READ_B(1, 1, bN1);
        MFMA_Q(0, 1, bN1);
        VM_LGKM_BAR(0);
        // P7
        READ_A(1, 1);
        MFMA_Q(1, 1, bN1);
        // P8
        MFMA_Q(1, 0, bN0);
    }
#undef READ_A
#undef READ_B
#undef MFMA_Q
#undef STG_A
#undef STG_B

    if (mode == 0) {
        const int part = row0 / 768;        // 768 % 256 == 0: uniform per block
        const int bb = col0 / 2048;         // 2048 % 256 == 0: uniform per block
        unsigned short* Xp = outb + (size_t)(part * 8 + bb) * 768 * 2048;
        const int drow0 = row0 - part * 768 + wr * 128 + (lane >> 4) * 4;
        const int lcol0 = col0 - bb * 2048 + wc * 64 + frow;
        #pragma unroll
        for (int m = 0; m < 8; ++m) {
            #pragma unroll
            for (int rr = 0; rr < 4; ++rr) {
                const int dd = drow0 + m * 16 + rr;
                const float bn = bias[row0 + wr * 128 + (lane >> 4) * 4 + m * 16 + rr];
                #pragma unroll
                for (int n = 0; n < 4; ++n)
                    Xp[dd * 2048 + lcol0 + n * 16] = f2b(acc[m][n][rr] + bn);
            }
        }
    } else {
        #pragma unroll
        for (int m = 0; m < 8; ++m) {
            #pragma unroll
            for (int rr = 0; rr < 4; ++rr) {
                const int mm = row0 + wr * 128 + (lane >> 4) * 4 + m * 16 + rr;
                #pragma unroll
                for (int n = 0; n < 4; ++n) {
                    const int nn = col0 + wc * 64 + n * 16 + frow;
                    outf[(size_t)mm * 768 + nn] = acc[m][n][rr] + bias[nn];
                }
            }
        }
    }
}

// --------------------- fused conv4 + gate + FFT conv -----------------------
__device__ __forceinline__ void conv6(const unsigned short* __restrict__ p,
                                      const float* w, float bias, int t, float* out8)
{
    const uint4 m = *(const uint4*)(p + 8 * t);
    uint2 q = make_uint2(0u, 0u);
    if (t) q = *(const uint2*)(p + 8 * t - 4);
    float s[12];
    s[0] = b2f_lo(q.x); s[1] = b2f_hi(q.x); s[2] = b2f_lo(q.y); s[3] = b2f_hi(q.y);
    s[4] = b2f_lo(m.x); s[5] = b2f_hi(m.x); s[6] = b2f_lo(m.y); s[7] = b2f_hi(m.y);
    s[8] = b2f_lo(m.z); s[9] = b2f_hi(m.z); s[10] = b2f_lo(m.w); s[11] = b2f_hi(m.w);
    #pragma unroll
    for (int i = 0; i < 8; ++i)
        out8[i] = bias + w[0] * s[i + 1] + w[1] * s[i + 2] + w[2] * s[i + 3] + w[3] * s[i + 4];
}

// grid (768, 4): x=d (same-d blocks 768 apart -> same XCD -> Kf L2 reuse)
// waves_per_eu(4,4): pin occupancy target so the allocator uses the full
// 512/4 = 128 VGPR budget (R9's spill fix).
__global__ __launch_bounds__(256) __attribute__((amdgpu_waves_per_eu(4, 4)))
void fft_conv_kernel(
    const unsigned short* __restrict__ X, const float2* __restrict__ Kf,
    const float* __restrict__ x1_s, const float* __restrict__ x2_s, const float* __restrict__ v_s,
    const float* __restrict__ x1_sb, const float* __restrict__ x2_sb, const float* __restrict__ v_sb,
    const float* __restrict__ D_bias, unsigned short* __restrict__ Y)
{
    __shared__ __align__(16) float2 lds[4096];
    unsigned* ldsu = (unsigned*)lds;
    const int d = blockIdx.x, jp = blockIdx.y, t = threadIdx.x;
    const int b0 = jp * 2, b1 = b0 + 1;

    float w1[4], w2[4], wv[4];
    #pragma unroll
    for (int j = 0; j < 4; ++j) { w1[j] = x1_s[d * 4 + j]; w2[j] = x2_s[d * 4 + j]; wv[j] = v_s[d * 4 + j]; }
    const float bc1 = x1_sb[d], bc2 = x2_sb[d], bcv = v_sb[d], Db = D_bias[d];

    const unsigned short* px1a = X + ((size_t)(0 * 8 + b0) * 768 + d) * 2048;
    const unsigned short* px2a = X + ((size_t)(1 * 8 + b0) * 768 + d) * 2048;
    const unsigned short* pva  = X + ((size_t)(2 * 8 + b0) * 768 + d) * 2048;
    const unsigned short* px1b = X + ((size_t)(0 * 8 + b1) * 768 + d) * 2048;
    const unsigned short* px2b = X + ((size_t)(1 * 8 + b1) * 768 + d) * 2048;
    const unsigned short* pvb  = X + ((size_t)(2 * 8 + b1) * 768 + d) * 2048;

    {
        float x1a[8], x2a[8], vva[8];
        conv6(px1a, w1, bc1, t, x1a);
        conv6(px2a, w2, bc2, t, x2a);
        conv6(pva,  wv, bcv, t, vva);
        float x1b[8], x2b[8], vvb[8];
        conv6(px1b, w1, bc1, t, x1b);
        conv6(px2b, w2, bc2, t, x2b);
        conv6(pvb,  wv, bcv, t, vvb);
        unsigned vh_pk[8], c2_pk[8];
        #pragma unroll
        for (int i = 0; i < 8; ++i) {
            vh_pk[i] = (unsigned)f2b(vva[i] * x1a[i]) | ((unsigned)f2b(vvb[i] * x1b[i]) << 16);
            c2_pk[i] = (unsigned)f2b(x2a[i]) | ((unsigned)f2b(x2b[i]) << 16);
        }
        *(uint4*)(ldsu + 8 * t)        = make_uint4(vh_pk[0], vh_pk[1], vh_pk[2], vh_pk[3]);
        *(uint4*)(ldsu + 8 * t + 4)    = make_uint4(vh_pk[4], vh_pk[5], vh_pk[6], vh_pk[7]);
        *(uint4*)(ldsu + 2048 + 8 * t)     = make_uint4(c2_pk[0], c2_pk[1], c2_pk[2], c2_pk[3]);
        *(uint4*)(ldsu + 2048 + 8 * t + 4) = make_uint4(c2_pk[4], c2_pk[5], c2_pk[6], c2_pk[7]);
    }
    __syncthreads();

    unsigned vhp[8], c2p[8];
    float2 x[16];
    #pragma unroll
    for (int r = 0; r < 8; ++r) {
        const unsigned u = ldsu[r * 256 + t];
        vhp[r] = u;
        x[r] = make_float2(b2f_lo(u), b2f_hi(u));
    }
    #pragma unroll
    for (int r = 0; r < 8; ++r) c2p[r] = ldsu[2048 + r * 256 + t];

    __syncthreads();

    fft4096_fwd(x, lds, t);

    // Kf loaded here (not held across the forward FFT): frees 32 VGPRs at
    // the register-pressure peak; Kf lines are L2-resident per-XCD.
    {
        const float2* kf = Kf + (size_t)d * 4096;
        float2 kfr[16];
        #pragma unroll
        for (int k3 = 0; k3 < 16; ++k3) kfr[k3] = kf[k3 * 256 + t];
        #pragma unroll
        for (int k3 = 0; k3 < 16; ++k3) x[k3] = cmul(x[k3], kfr[k3]);
    }
    fft4096_inv(x, lds, t);

    // Kf pre-scaled by 1/4096: x already carries irfft normalization.
    unsigned short* ya = Y + ((size_t)b0 * 768 + d) * 2048;
    unsigned short* yb = Y + ((size_t)b1 * 768 + d) * 2048;
    #pragma unroll
    for (int n1 = 0; n1 < 8; ++n1) {
        const int l = n1 * 256 + t;
        const float va = b2f_lo(vhp[n1]);
        const float vb = b2f_hi(vhp[n1]);
        const float ca = b2f_lo(c2p[n1]);
        const float cb = b2f_hi(c2p[n1]);
        ya[l] = f2b((x[n1].x + va * Db) * ca);
        yb[l] = f2b((x[n1].y + vb * Db) * cb);
    }
}

// --------------------------------- launch ----------------------------------
extern "C" void kernel_launch(void* const* d_in, const int* in_sizes, int n_in,
                              void* d_out, int out_size, void* d_ws, size_t ws_size,
                              hipStream_t stream)
{
    (void)in_sizes; (void)n_in; (void)out_size; (void)ws_size;
    const float* u      = (const float*)d_in[0];
    const float* in_W   = (const float*)d_in[1];
    const float* in_b   = (const float*)d_in[2];
    const float* out_W  = (const float*)d_in[3];
    const float* out_b  = (const float*)d_in[4];
    const float* x1_s   = (const float*)d_in[5];
    const float* x2_s   = (const float*)d_in[6];
    const float* v_s    = (const float*)d_in[7];
    const float* x1_sb  = (const float*)d_in[8];
    const float* x2_sb  = (const float*)d_in[9];
    const float* v_sb   = (const float*)d_in[10];
    const float* D_bias = (const float*)d_in[11];
    const float* z      = (const float*)d_in[12];
    const float* sf     = (const float*)d_in[13];
    const float* eo     = (const float*)d_in[14];
    const float* eo_b   = (const float*)d_in[15];
    const float* oo1    = (const float*)d_in[16];
    const float* oo1_b  = (const float*)d_in[17];
    const float* oo2    = (const float*)d_in[18];
    const float* oo2_b  = (const float*)d_in[19];
    const float* oh     = (const float*)d_in[20];
    float* out = (float*)d_out;

    char* ws = (char*)d_ws;
    unsigned short* Xbf  = (unsigned short*)(ws + 0);          //  75,497,472 X[3][8][768][2048] bf16
    unsigned short* Ybf  = (unsigned short*)(ws + 75497472);   //  25,165,824 Y[8][768][2048] bf16
    unsigned short* ubYt = (unsigned short*)(ws + 100663296);  //  25,165,824 ub, later aliased as Yt
    unsigned short* Wt   = (unsigned short*)(ws + 125829120);  //   3,538,944 Wt[2304][768] bf16
    unsigned short* W2t  = (unsigned short*)(ws + 129368064);  //   1,179,648 W2t[768][768] bf16
    float*          kfil = (float*)(ws + 130547712);           //   6,291,456 k[768][2048] fp32
    float2*         Kf   = (float2*)(ws + 136839168);          //  25,165,824 K_f[768][16][256] cplx (permuted, pre-scaled 1/4096)

    static int attr_set = 0;
    if (!attr_set) {
        (void)hipFuncSetAttribute(reinterpret_cast<const void*>(gemm256_kernel),
                                  hipFuncAttributeMaxDynamicSharedMemorySize, 131072);
        attr_set = 1;
    }

    twiddle_init_kernel<<<17, 256, 0, stream>>>();
    filter_k_kernel<<<512, 256, 0, stream>>>(z, sf, eo, eo_b, oo1, oo1_b, oo2, oo2_b, oh, kfil);
    filter_fft_kernel<<<768, 256, 0, stream>>>(kfil, Kf);
    convert_u_kernel<<<12288, 256, 0, stream>>>(u, ubYt);
    transpose_W_kernel<<<dim3(72, 24), 256, 0, stream>>>(in_W, Wt, 768, 2304);
    transpose_W_kernel<<<dim3(24, 24), 256, 0, stream>>>(out_W, W2t, 768, 768);
    gemm256_kernel<<<dim3(64, 9), 512, 131072, stream>>>(Wt, ubYt, in_b, Xbf, nullptr, 0);
    fft_conv_kernel<<<dim3(768, 4), 256, 0, stream>>>(Xbf, Kf, x1_s, x2_s, v_s, x1_sb, x2_sb, v_sb, D_bias, Ybf);
    transpose_Y_kernel<<<12288, 256, 0, stream>>>(Ybf, ubYt);
    gemm256_kernel<<<dim3(64, 3), 512, 131072, stream>>>(ubYt, W2t, out_b, nullptr, out, 1);
}

// Round 4
// 361.588 us; speedup vs baseline: 1.3742x; 1.1848x over previous
//
#include <hip/hip_runtime.h>

// ---------------------------------------------------------------------------
// FlashMMSequenceMixing (Hyena-style): B=8, L=2048, D=768, ORDER=128, FFT=4096
// R10 -> R11: stop fighting the register allocator; shrink the fft_conv
// working set below 64 VGPRs so the allocator's preferred 8-wave/64-VGPR
// allocation is spill-free (R10 counters: VGPR 64 + WRITE_SIZE 172MB vs
// 25MB ideal = ~147MB scratch writes; waves_per_eu didn't move the target).
//  1) D_bias folded into Kf (irfft linearity: irfft(Vf*Kf)+v*Db =
//     irfft(Vf*(Kf+Db)), delta at lag0 = no circular-wrap term). Kills the
//     vhp[8] registers held across both FFTs and their packing path.
//  2) x2 gate recomputed AFTER the inverse FFT (re-reads 24MB of X, +3us)
//     and passed through the now-free LDS transpose. Kills c2p[8] held regs.
//  3) Twiddles by power-split {1,w,w2,w3}x{1,w4,w8,w12} applied in place:
//     12 regs live (was 30 for the w[16] array / table loads). Twiddle
//     tables + init kernel deleted. Kf multiply chunked 4-wide with
//     compiler fences so loads aren't hoisted into 32 live regs.
//  Peak live ~54-62 -> no scratch. No occupancy attributes; 32KiB LDS ->
//  5 blocks/CU. GEMM unchanged.
// ---------------------------------------------------------------------------

typedef __bf16 bf16x8 __attribute__((ext_vector_type(8)));
typedef float  f32x4  __attribute__((ext_vector_type(4)));

#define AS1 __attribute__((address_space(1)))
#define AS3 __attribute__((address_space(3)))
#define GLD16(gp, lp) __builtin_amdgcn_global_load_lds((AS1 void*)(void*)(gp), (AS3 void*)(void*)(lp), 16, 0, 0)

// compiler-visible fences (memory clobber pins LDS/global ops to program order)
#define LGKM_BAR       __asm__ __volatile__("s_waitcnt lgkmcnt(0)\n\ts_barrier" ::: "memory")
#define VM_LGKM_BAR(N) __asm__ __volatile__("s_waitcnt vmcnt(" #N ") lgkmcnt(0)\n\ts_barrier" ::: "memory")

__device__ __forceinline__ unsigned short f2b(float f) {
    unsigned u = __builtin_bit_cast(unsigned, f);
    unsigned r = (u + 0x7fffu + ((u >> 16) & 1u)) >> 16;
    return (unsigned short)r;
}
__device__ __forceinline__ float b2f_lo(unsigned u) {
    return __builtin_bit_cast(float, u << 16);
}
__device__ __forceinline__ float b2f_hi(unsigned u) {
    return __builtin_bit_cast(float, u & 0xffff0000u);
}

__device__ __forceinline__ float2 cmul(float2 a, float2 b) {
    return make_float2(a.x * b.x - a.y * b.y, a.x * b.y + a.y * b.x);
}
__device__ __forceinline__ float2 cadd(float2 a, float2 b) { return make_float2(a.x + b.x, a.y + b.y); }
__device__ __forceinline__ float2 csub(float2 a, float2 b) { return make_float2(a.x - b.x, a.y - b.y); }

#define TWO_PI 6.283185307179586f

// ------------------------- 16-point register DFT ---------------------------
#define BFLY(i,j)   { float2 ta=x[i], tb=x[j]; x[i]=cadd(ta,tb); x[j]=csub(ta,tb); }
#define BFLYW(i,j,w){ float2 ta=x[i], tb=x[j]; x[i]=cadd(ta,tb); x[j]=cmul(csub(ta,tb),(w)); }
#define BFLYI(i,j)  { float2 ta=x[i], tb=x[j]; x[i]=cadd(ta,tb); float2 tt=csub(ta,tb); x[j]=make_float2(-dd*tt.y, dd*tt.x); }
#define CSWAP(i,j)  { float2 tt=x[i]; x[i]=x[j]; x[j]=tt; }

template<int DIR, bool UZ>
__device__ __forceinline__ void dft16(float2* x) {
    const float dd = (float)DIR;
    const float C1 = 0.92387953251128674f, S1 = 0.38268343236508977f, R2 = 0.70710678118654752f;
    const float2 W1 = make_float2( C1, dd*S1);
    const float2 W2 = make_float2( R2, dd*R2);
    const float2 W3 = make_float2( S1, dd*C1);
    const float2 W5 = make_float2(-S1, dd*C1);
    const float2 W6 = make_float2(-R2, dd*R2);
    const float2 W7 = make_float2(-C1, dd*S1);
    if (UZ) {
        x[8]  = x[0];
        x[9]  = cmul(x[1], W1);
        x[10] = cmul(x[2], W2);
        x[11] = cmul(x[3], W3);
        x[12] = make_float2(-dd*x[4].y, dd*x[4].x);
        x[13] = cmul(x[5], W5);
        x[14] = cmul(x[6], W6);
        x[15] = cmul(x[7], W7);
    } else {
        BFLY(0,8); BFLYW(1,9,W1); BFLYW(2,10,W2); BFLYW(3,11,W3);
        BFLYI(4,12); BFLYW(5,13,W5); BFLYW(6,14,W6); BFLYW(7,15,W7);
    }
    BFLY(0,4);  BFLYW(1,5,W2);  BFLYI(2,6);   BFLYW(3,7,W6);
    BFLY(8,12); BFLYW(9,13,W2); BFLYI(10,14); BFLYW(11,15,W6);
    BFLY(0,2);  BFLYI(1,3);  BFLY(4,6);   BFLYI(5,7);
    BFLY(8,10); BFLYI(9,11); BFLY(12,14); BFLYI(13,15);
    BFLY(0,1); BFLY(2,3); BFLY(4,5); BFLY(6,7);
    BFLY(8,9); BFLY(10,11); BFLY(12,13); BFLY(14,15);
    CSWAP(1,8); CSWAP(2,4); CSWAP(3,12); CSWAP(5,10); CSWAP(7,14); CSWAP(11,13);
}

// twiddle by power-split: x[4a+b] *= w^(4a) * w^b. 6 complex (12 VGPR) live,
// each product consumed immediately. dep depth ~3 cmuls after sincos.
__device__ __forceinline__ void twiddle16(float2* x, float ang) {
    float s, c; __sincosf(ang, &s, &c);
    const float2 u1  = make_float2(c, s);
    const float2 u2  = cmul(u1, u1);
    const float2 u3  = cmul(u2, u1);
    const float2 u4  = cmul(u2, u2);
    const float2 u8  = cmul(u4, u4);
    const float2 u12 = cmul(u8, u4);
    x[1]  = cmul(x[1],  u1);
    x[2]  = cmul(x[2],  u2);
    x[3]  = cmul(x[3],  u3);
    x[4]  = cmul(x[4],  u4);
    x[5]  = cmul(x[5],  cmul(u4, u1));
    x[6]  = cmul(x[6],  cmul(u4, u2));
    x[7]  = cmul(x[7],  cmul(u4, u3));
    x[8]  = cmul(x[8],  u8);
    x[9]  = cmul(x[9],  cmul(u8, u1));
    x[10] = cmul(x[10], cmul(u8, u2));
    x[11] = cmul(x[11], cmul(u8, u3));
    x[12] = cmul(x[12], u12);
    x[13] = cmul(x[13], cmul(u12, u1));
    x[14] = cmul(x[14], cmul(u12, u2));
    x[15] = cmul(x[15], cmul(u12, u3));
}

// physical LDS index (float2 units), XOR-swizzled exact-stride layouts.
// Round 1: logical (row k1<16, col t<256): bank set = low4 of (col^row).
// Round 2: logical (row t<256, col k2<16): bank set = low4 of (col^row).
// All wave accesses hit 16 distinct bank-pair slots x 4 lanes = the 4-beat
// minimum for 8B/lane (same as 272/17 stride padding, at 32KiB total).
__device__ __forceinline__ int ph1(int row, int col) { return row * 256 + (col ^ row); }
__device__ __forceinline__ int ph2(int row, int col) { return row * 16 + (col ^ (row & 15)); }

__device__ __forceinline__ void fft4096_fwd(float2* x, float2* lds, int t) {
    dft16<-1, true>(x);
    twiddle16(x, -(float)t * (TWO_PI / 4096.0f));
    #pragma unroll
    for (int k1 = 0; k1 < 16; ++k1) lds[ph1(k1, t)] = x[k1];
    __syncthreads();
    const int hi = t >> 4, lo = t & 15;
    #pragma unroll
    for (int t1 = 0; t1 < 16; ++t1) x[t1] = lds[ph1(hi, t1 * 16 + lo)];
    dft16<-1, false>(x);
    twiddle16(x, -(float)lo * (TWO_PI / 256.0f));
    __syncthreads();
    #pragma unroll
    for (int k2 = 0; k2 < 16; ++k2) lds[ph2(t, k2)] = x[k2];
    __syncthreads();
    #pragma unroll
    for (int t0 = 0; t0 < 16; ++t0) x[t0] = lds[ph2(hi * 16 + t0, lo)];
    dft16<-1, false>(x);
}

__device__ __forceinline__ void fft4096_inv(float2* x, float2* lds, int t) {
    const int hi = t >> 4, lo = t & 15;
    dft16<1, false>(x);
    __syncthreads();
    #pragma unroll
    for (int t0 = 0; t0 < 16; ++t0) lds[ph2(hi * 16 + t0, lo)] = x[t0];
    __syncthreads();
    #pragma unroll
    for (int k2 = 0; k2 < 16; ++k2) x[k2] = lds[ph2(t, k2)];
    twiddle16(x, (float)lo * (TWO_PI / 256.0f));
    dft16<1, false>(x);
    __syncthreads();
    #pragma unroll
    for (int t1 = 0; t1 < 16; ++t1) lds[ph1(hi, t1 * 16 + lo)] = x[t1];
    __syncthreads();
    #pragma unroll
    for (int k1 = 0; k1 < 16; ++k1) x[k1] = lds[ph1(k1, t)];
    twiddle16(x, (float)t * (TWO_PI / 4096.0f));
    dft16<1, false>(x);
}

// ------------------------------- filter MLP --------------------------------
// 512 blocks x 4 rows: 2 blocks/CU (2 waves/SIMD) to hide the serial q-loop
// latency.
__global__ __launch_bounds__(256) void filter_k_kernel(
    const float* __restrict__ z, const float* __restrict__ sf,
    const float* __restrict__ eo, const float* __restrict__ eo_b,
    const float* __restrict__ oo1, const float* __restrict__ oo1_b,
    const float* __restrict__ oo2, const float* __restrict__ oo2_b,
    const float* __restrict__ oh, float* __restrict__ kfil)
{
    __shared__ float h3buf[4][128];
    __shared__ float htmp[2][128];
    const int t = threadIdx.x;
    const int l0 = blockIdx.x * 4;
    const int half = t >> 7;
    const int o = t & 127;
    const float sfo = sf[o];
    for (int p = 0; p < 2; ++p) {
        const int li = p * 2 + half;
        const int l = l0 + li;
        float a = eo_b[o];
        #pragma unroll
        for (int e = 0; e < 5; ++e) a += z[l * 5 + e] * eo[e * 128 + o];
        htmp[half][o] = sinf(sfo * a);
        __syncthreads();
        float a2 = oo1_b[o];
        for (int q = 0; q < 128; ++q) a2 += htmp[half][q] * oo1[q * 128 + o];
        const float h2 = sinf(sfo * a2);
        __syncthreads();
        htmp[half][o] = h2;
        __syncthreads();
        float a3 = oo2_b[o];
        for (int q = 0; q < 128; ++q) a3 += htmp[half][q] * oo2[q * 128 + o];
        h3buf[li][o] = sinf(sfo * a3);
        __syncthreads();
    }
    const float MIND = -3.070113457325394f;
    const float MAXD = -15.350567286626972f;
    for (int c = 0; c < 3; ++c) {
        const int h = t + c * 256;
        float acc[4];
        #pragma unroll
        for (int li = 0; li < 4; ++li) acc[li] = 0.f;
        for (int q = 0; q < 128; ++q) {
            const float w = oh[q * 768 + h];
            #pragma unroll
            for (int li = 0; li < 4; ++li) acc[li] += h3buf[li][q] * w;
        }
        const float delta = fabsf(MIND + (MAXD - MIND) * (float)h * (1.0f / 767.0f));
        #pragma unroll
        for (int li = 0; li < 4; ++li) {
            const int l = l0 + li;
            const float tt = (float)l * (1.0f / 2047.0f);
            kfil[h * 2048 + l] = acc[li] * expf(-tt * delta);
        }
    }
}

// --------------------------- filter FFT ------------------------------------
// Stores Kf' = (FFT(k) + D_bias[d]) / 4096: both the irfft normalization AND
// the D_bias*v skip-connection folded in (FFT(Db*delta0) = Db on every bin).
__global__ __launch_bounds__(256) void filter_fft_kernel(
    const float* __restrict__ kfil, const float* __restrict__ D_bias,
    float2* __restrict__ Kf)
{
    __shared__ __align__(16) float2 lds[4096];
    const int d = blockIdx.x, t = threadIdx.x;
    float2 x[16];
    #pragma unroll
    for (int r = 0; r < 8; ++r) x[r] = make_float2(kfil[d * 2048 + r * 256 + t], 0.f);
    fft4096_fwd(x, lds, t);
    const float db = D_bias[d];
    const float s = 1.0f / 4096.0f;
    #pragma unroll
    for (int k3 = 0; k3 < 16; ++k3)
        Kf[d * 4096 + k3 * 256 + t] = make_float2((x[k3].x + db) * s, x[k3].y * s);
}

// --------------------------- conversions/transposes ------------------------
__global__ __launch_bounds__(256) void convert_u_kernel(
    const float* __restrict__ u, unsigned short* __restrict__ ub)
{
    const int g = blockIdx.x * 256 + threadIdx.x;
    const float4 v = ((const float4*)u)[g];
    uint2 o;
    o.x = (unsigned)f2b(v.x) | ((unsigned)f2b(v.y) << 16);
    o.y = (unsigned)f2b(v.z) | ((unsigned)f2b(v.w) << 16);
    ((uint2*)ub)[g] = o;
}

__global__ __launch_bounds__(256) void transpose_W_kernel(
    const float* __restrict__ W, unsigned short* __restrict__ Wt, int K, int N)
{
    __shared__ float tile[32][33];
    const int n0 = blockIdx.x * 32, k0 = blockIdx.y * 32;
    const int tx = threadIdx.x & 31, ty = threadIdx.x >> 5;
    #pragma unroll
    for (int r = 0; r < 4; ++r) {
        const int kk = ty + r * 8;
        tile[kk][tx] = W[(k0 + kk) * N + n0 + tx];
    }
    __syncthreads();
    #pragma unroll
    for (int r = 0; r < 4; ++r) {
        const int nn = ty + r * 8;
        Wt[(n0 + nn) * K + k0 + tx] = f2b(tile[tx][nn]);
    }
}

__global__ __launch_bounds__(256) void transpose_Y_kernel(
    const unsigned short* __restrict__ Y, unsigned short* __restrict__ Yt)
{
    __shared__ unsigned short tile[32][34];
    const int bx = blockIdx.x;
    const int l0 = (bx & 63) * 32;
    const int tmp = bx >> 6;
    const int d0 = (tmp % 24) * 32;
    const int b  = tmp / 24;
    const int tx = threadIdx.x & 31, ty = threadIdx.x >> 5;
    #pragma unroll
    for (int r = 0; r < 4; ++r) {
        const int dd = ty + r * 8;
        tile[dd][tx] = Y[(b * 768 + d0 + dd) * 2048 + l0 + tx];
    }
    __syncthreads();
    #pragma unroll
    for (int r = 0; r < 4; ++r) {
        const int ll = ty + r * 8;
        Yt[(b * 2048 + l0 + ll) * 768 + d0 + tx] = tile[tx][ll];
    }
}

// ------------------------------- bf16 GEMM ---------------------------------
// 256x256 tile, BK=64, 8 waves (2Mx4N), wave tile 128x64, 8-phase schedule.
// (unchanged from R8 — see that round's header for the stage/fence proof)
__global__ __launch_bounds__(512, 2) void gemm256_kernel(
    const unsigned short* __restrict__ A,
    const unsigned short* __restrict__ Bm,
    const float* __restrict__ bias,
    unsigned short* __restrict__ outb,
    float* __restrict__ outf,
    int mode)
{
    extern __shared__ __align__(16) unsigned short lds[];
    unsigned short* As = lds;            // [2][256][64]  2*32 KiB
    unsigned short* Bs = lds + 32768;    // [2][256][64]  2*32 KiB
    const int t = threadIdx.x;
    const int wv = t >> 6, lane = t & 63;
    const int row0 = (mode == 0 ? blockIdx.y : blockIdx.x) * 256;
    const int col0 = (mode == 0 ? blockIdx.x : blockIdx.y) * 256;
    const int wr = wv >> 2, wc = wv & 3;
    const int frow = lane & 15, kc = lane >> 4;

    f32x4 acc[8][4] = {};

    const int srow = t >> 3;
    const int cdat = (t & 7) ^ (srow & 7);
    const unsigned short* gA = A  + (row0 + srow) * 768 + cdat * 8;
    const unsigned short* gB = Bm + (col0 + srow) * 768 + cdat * 8;

#define STG_A(buf, q, koff) GLD16(gA + (q) * 49152 + (koff), (char*)As + (buf) * 32768 + (q) * 8192 + wv * 1024)
#define STG_B(buf, q, koff) GLD16(gB + (q) * 49152 + (koff), (char*)Bs + (buf) * 32768 + (q) * 8192 + wv * 1024)

    const int sx = frow & 7;
    const int aRowBase = (wr * 128 + frow) * 64;
    const int bRowBase = (wc * 64 + frow) * 64;
    const int sl0 = ((0 + kc) ^ sx) * 8;   // K-sub 0
    const int sl1 = ((4 + kc) ^ sx) * 8;   // K-sub 1

    bf16x8 aF[4][2], bN0[2][2], bN1[2][2];

#define READ_A(buf, mh)                                                         \
    _Pragma("unroll") for (int m = 0; m < 4; ++m) {                             \
        aF[m][0] = *(const bf16x8*)(As + (buf) * 16384 + aRowBase + ((mh) * 4 + m) * 1024 + sl0); \
        aF[m][1] = *(const bf16x8*)(As + (buf) * 16384 + aRowBase + ((mh) * 4 + m) * 1024 + sl1); \
    }
#define READ_B(buf, nh, arr)                                                    \
    _Pragma("unroll") for (int n = 0; n < 2; ++n) {                             \
        arr[n][0] = *(const bf16x8*)(Bs + (buf) * 16384 + bRowBase + ((nh) * 2 + n) * 1024 + sl0); \
        arr[n][1] = *(const bf16x8*)(Bs + (buf) * 16384 + bRowBase + ((nh) * 2 + n) * 1024 + sl1); \
    }
#define MFMA_Q(mh, nh, arr)                                                     \
    __builtin_amdgcn_s_setprio(1);                                              \
    _Pragma("unroll") for (int m = 0; m < 4; ++m)                               \
    _Pragma("unroll") for (int n = 0; n < 2; ++n)                               \
    _Pragma("unroll") for (int ks = 0; ks < 2; ++ks)                            \
        acc[(mh) * 4 + m][(nh) * 2 + n] = __builtin_amdgcn_mfma_f32_16x16x32_bf16( \
            aF[m][ks], arr[n][ks], acc[(mh) * 4 + m][(nh) * 2 + n], 0, 0, 0);   \
    __builtin_amdgcn_s_setprio(0);

    // prologue: tile 0 complete (8 issues, oldest) + tile 1 minus Aq1/Aq3
    STG_A(0, 0, 0); STG_A(0, 1, 0); STG_A(0, 2, 0); STG_A(0, 3, 0);
    STG_B(0, 0, 0); STG_B(0, 1, 0); STG_B(0, 2, 0); STG_B(0, 3, 0);
    STG_A(1, 0, 64); STG_A(1, 2, 64);
    STG_B(1, 0, 64); STG_B(1, 1, 64); STG_B(1, 2, 64); STG_B(1, 3, 64);
    VM_LGKM_BAR(6);   // forces the oldest 8 (= tile 0) landed

    for (int i = 0; i < 5; ++i) {
        const int k1 = (2 * i + 1) * 64, k2 = (2 * i + 2) * 64, k3 = (2 * i + 3) * 64;
        // P1: Qa(buf0)
        READ_A(0, 0); READ_B(0, 0, bN0);
        STG_A(1, 1, k1); STG_A(1, 3, k1);
        MFMA_Q(0, 0, bN0);
        LGKM_BAR;
        // P2: Qb(buf0)
        READ_B(0, 1, bN1);
        STG_A(0, 0, k2); STG_A(0, 2, k2);
        MFMA_Q(0, 1, bN1);
        LGKM_BAR;
        // P3: Qc(buf0)
        READ_A(0, 1);
        STG_B(0, 0, k2); STG_B(0, 1, k2);
        MFMA_Q(1, 1, bN1);
        LGKM_BAR;
        // P4: Qd(buf0) — register reuse only
        STG_B(0, 2, k2); STG_B(0, 3, k2);
        MFMA_Q(1, 0, bN0);
        VM_LGKM_BAR(6);
        // P5: Qa(buf1)
        READ_A(1, 0); READ_B(1, 0, bN0);
        STG_A(0, 1, k2); STG_A(0, 3, k2);
        MFMA_Q(0, 0, bN0);
        LGKM_BAR;
        // P6: Qb(buf1)
        READ_B(1, 1, bN1);
        STG_A(1, 0, k3); STG_A(1, 2, k3);
        MFMA_Q(0, 1, bN1);
        LGKM_BAR;
        // P7: Qc(buf1)
        READ_A(1, 1);
        STG_B(1, 0, k3); STG_B(1, 1, k3);
        MFMA_Q(1, 1, bN1);
        LGKM_BAR;
        // P8: Qd(buf1)
        STG_B(1, 2, k3); STG_B(1, 3, k3);
        MFMA_Q(1, 0, bN0);
        VM_LGKM_BAR(6);
    }

    // epilogue: tiles 10 (buf0) and 11 (buf1); only P1's stage remains
    {
        // P1
        READ_A(0, 0); READ_B(0, 0, bN0);
        STG_A(1, 1, 704); STG_A(1, 3, 704);   // tile 11 tail
        MFMA_Q(0, 0, bN0);
        LGKM_BAR;
        // P2
        READ_B(0, 1, bN1);
        MFMA_Q(0, 1, bN1);
        LGKM_BAR;
        // P3
        READ_A(0, 1);
        MFMA_Q(1, 1, bN1);
        LGKM_BAR;
        // P4 — forces tile 11 body (i4 P6..P8 issues) landed
        MFMA_Q(1, 0, bN0);
        VM_LGKM_BAR(2);
        // P5
        READ_A(1, 0); READ_B(1, 0, bN0);
        MFMA_Q(0, 0, bN0);
        LGKM_BAR;
        // P6 — forces tile 11 Aq1/Aq3 landed; vmcnt==0 from here on
        READ_B(1, 1, bN1);
        MFMA_Q(0, 1, bN1);
        VM_LGKM_BAR(0);
        // P7
        READ_A(1, 1);
        MFMA_Q(1, 1, bN1);
        // P8
        MFMA_Q(1, 0, bN0);
    }
#undef READ_A
#undef READ_B
#undef MFMA_Q
#undef STG_A
#undef STG_B

    if (mode == 0) {
        const int part = row0 / 768;        // 768 % 256 == 0: uniform per block
        const int bb = col0 / 2048;         // 2048 % 256 == 0: uniform per block
        unsigned short* Xp = outb + (size_t)(part * 8 + bb) * 768 * 2048;
        const int drow0 = row0 - part * 768 + wr * 128 + (lane >> 4) * 4;
        const int lcol0 = col0 - bb * 2048 + wc * 64 + frow;
        #pragma unroll
        for (int m = 0; m < 8; ++m) {
            #pragma unroll
            for (int rr = 0; rr < 4; ++rr) {
                const int dd = drow0 + m * 16 + rr;
                const float bn = bias[row0 + wr * 128 + (lane >> 4) * 4 + m * 16 + rr];
                #pragma unroll
                for (int n = 0; n < 4; ++n)
                    Xp[dd * 2048 + lcol0 + n * 16] = f2b(acc[m][n][rr] + bn);
            }
        }
    } else {
        #pragma unroll
        for (int m = 0; m < 8; ++m) {
            #pragma unroll
            for (int rr = 0; rr < 4; ++rr) {
                const int mm = row0 + wr * 128 + (lane >> 4) * 4 + m * 16 + rr;
                #pragma unroll
                for (int n = 0; n < 4; ++n) {
                    const int nn = col0 + wc * 64 + n * 16 + frow;
                    outf[(size_t)mm * 768 + nn] = acc[m][n][rr] + bias[nn];
                }
            }
        }
    }
}

// --------------------- fused conv4 + gate + FFT conv -----------------------
__device__ __forceinline__ void conv6(const unsigned short* __restrict__ p,
                                      const float* w, float bias, int t, float* out8)
{
    const uint4 m = *(const uint4*)(p + 8 * t);
    uint2 q = make_uint2(0u, 0u);
    if (t) q = *(const uint2*)(p + 8 * t - 4);
    float s[12];
    s[0] = b2f_lo(q.x); s[1] = b2f_hi(q.x); s[2] = b2f_lo(q.y); s[3] = b2f_hi(q.y);
    s[4] = b2f_lo(m.x); s[5] = b2f_hi(m.x); s[6] = b2f_lo(m.y); s[7] = b2f_hi(m.y);
    s[8] = b2f_lo(m.z); s[9] = b2f_hi(m.z); s[10] = b2f_lo(m.w); s[11] = b2f_hi(m.w);
    #pragma unroll
    for (int i = 0; i < 8; ++i)
        out8[i] = bias + w[0] * s[i + 1] + w[1] * s[i + 2] + w[2] * s[i + 3] + w[3] * s[i + 4];
}

// grid (768, 4): x=d (same-d blocks 768 apart -> same XCD -> Kf L2 reuse)
// D_bias is folded into Kf (see filter_fft); x2 gate recomputed after the
// inverse FFT and passed through the LDS transpose. Working set < 64 VGPR.
__global__ __launch_bounds__(256) void fft_conv_kernel(
    const unsigned short* __restrict__ X, const float2* __restrict__ Kf,
    const float* __restrict__ x1_s, const float* __restrict__ x2_s, const float* __restrict__ v_s,
    const float* __restrict__ x1_sb, const float* __restrict__ x2_sb, const float* __restrict__ v_sb,
    unsigned short* __restrict__ Y)
{
    __shared__ __align__(16) float2 lds[4096];
    unsigned* ldsu = (unsigned*)lds;
    const int d = blockIdx.x, jp = blockIdx.y, t = threadIdx.x;
    const int b0 = jp * 2, b1 = b0 + 1;

    const unsigned short* px1a = X + ((size_t)(0 * 8 + b0) * 768 + d) * 2048;
    const unsigned short* pva  = X + ((size_t)(2 * 8 + b0) * 768 + d) * 2048;
    const unsigned short* px1b = X + ((size_t)(0 * 8 + b1) * 768 + d) * 2048;
    const unsigned short* pvb  = X + ((size_t)(2 * 8 + b1) * 768 + d) * 2048;

    // ---- v * x1 gate, b0 then b1 (halved live set), pack pairs into LDS ----
    {
        float w1[4], wv[4];
        #pragma unroll
        for (int j = 0; j < 4; ++j) { w1[j] = x1_s[d * 4 + j]; wv[j] = v_s[d * 4 + j]; }
        const float bc1 = x1_sb[d], bcv = v_sb[d];
        float pa[8];
        {
            float va[8], g[8];
            conv6(pva,  wv, bcv, t, va);
            conv6(px1a, w1, bc1, t, g);
            #pragma unroll
            for (int i = 0; i < 8; ++i) pa[i] = va[i] * g[i];
        }
        {
            float vb[8], g[8];
            conv6(pvb,  wv, bcv, t, vb);
            conv6(px1b, w1, bc1, t, g);
            unsigned vh[8];
            #pragma unroll
            for (int i = 0; i < 8; ++i)
                vh[i] = (unsigned)f2b(pa[i]) | ((unsigned)f2b(vb[i] * g[i]) << 16);
            *(uint4*)(ldsu + 8 * t)     = make_uint4(vh[0], vh[1], vh[2], vh[3]);
            *(uint4*)(ldsu + 8 * t + 4) = make_uint4(vh[4], vh[5], vh[6], vh[7]);
        }
    }
    __syncthreads();

    float2 x[16];
    #pragma unroll
    for (int r = 0; r < 8; ++r) {
        const unsigned u = ldsu[r * 256 + t];
        x[r] = make_float2(b2f_lo(u), b2f_hi(u));
    }
    __syncthreads();

    fft4096_fwd(x, lds, t);

    // pointwise multiply by Kf' (= (FFT(k)+Db)/4096); 4-wide chunks with
    // fences so the compiler doesn't hoist 16 loads into 32 live regs.
    {
        const float2* kf = Kf + (size_t)d * 4096;
        #pragma unroll
        for (int c4 = 0; c4 < 4; ++c4) {
            float2 kr[4];
            #pragma unroll
            for (int j = 0; j < 4; ++j) kr[j] = kf[(c4 * 4 + j) * 256 + t];
            #pragma unroll
            for (int j = 0; j < 4; ++j) x[c4 * 4 + j] = cmul(x[c4 * 4 + j], kr[j]);
            __asm__ __volatile__("" ::: "memory");
        }
    }

    fft4096_inv(x, lds, t);

    // ---- x2 gate: recompute, transpose through LDS, apply, store ----
    __syncthreads();   // all lanes done with inv-FFT's final LDS reads
    {
        const unsigned short* px2a = X + ((size_t)(1 * 8 + b0) * 768 + d) * 2048;
        const unsigned short* px2b = X + ((size_t)(1 * 8 + b1) * 768 + d) * 2048;
        float w2[4];
        #pragma unroll
        for (int j = 0; j < 4; ++j) w2[j] = x2_s[d * 4 + j];
        const float bc2 = x2_sb[d];
        float ga[8], gb[8];
        conv6(px2a, w2, bc2, t, ga);
        conv6(px2b, w2, bc2, t, gb);
        unsigned c2[8];
        #pragma unroll
        for (int i = 0; i < 8; ++i)
            c2[i] = (unsigned)f2b(ga[i]) | ((unsigned)f2b(gb[i]) << 16);
        *(uint4*)(ldsu + 8 * t)     = make_uint4(c2[0], c2[1], c2[2], c2[3]);
        *(uint4*)(ldsu + 8 * t + 4) = make_uint4(c2[4], c2[5], c2[6], c2[7]);
    }
    __syncthreads();

    unsigned short* ya = Y + ((size_t)b0 * 768 + d) * 2048;
    unsigned short* yb = Y + ((size_t)b1 * 768 + d) * 2048;
    #pragma unroll
    for (int n1 = 0; n1 < 8; ++n1) {
        const int l = n1 * 256 + t;
        const unsigned u = ldsu[l];
        ya[l] = f2b(x[n1].x * b2f_lo(u));
        yb[l] = f2b(x[n1].y * b2f_hi(u));
    }
}

// --------------------------------- launch ----------------------------------
extern "C" void kernel_launch(void* const* d_in, const int* in_sizes, int n_in,
                              void* d_out, int out_size, void* d_ws, size_t ws_size,
                              hipStream_t stream)
{
    (void)in_sizes; (void)n_in; (void)out_size; (void)ws_size;
    const float* u      = (const float*)d_in[0];
    const float* in_W   = (const float*)d_in[1];
    const float* in_b   = (const float*)d_in[2];
    const float* out_W  = (const float*)d_in[3];
    const float* out_b  = (const float*)d_in[4];
    const float* x1_s   = (const float*)d_in[5];
    const float* x2_s   = (const float*)d_in[6];
    const float* v_s    = (const float*)d_in[7];
    const float* x1_sb  = (const float*)d_in[8];
    const float* x2_sb  = (const float*)d_in[9];
    const float* v_sb   = (const float*)d_in[10];
    const float* D_bias = (const float*)d_in[11];
    const float* z      = (const float*)d_in[12];
    const float* sf     = (const float*)d_in[13];
    const float* eo     = (const float*)d_in[14];
    const float* eo_b   = (const float*)d_in[15];
    const float* oo1    = (const float*)d_in[16];
    const float* oo1_b  = (const float*)d_in[17];
    const float* oo2    = (const float*)d_in[18];
    const float* oo2_b  = (const float*)d_in[19];
    const float* oh     = (const float*)d_in[20];
    float* out = (float*)d_out;

    char* ws = (char*)d_ws;
    unsigned short* Xbf  = (unsigned short*)(ws + 0);          //  75,497,472 X[3][8][768][2048] bf16
    unsigned short* Ybf  = (unsigned short*)(ws + 75497472);   //  25,165,824 Y[8][768][2048] bf16
    unsigned short* ubYt = (unsigned short*)(ws + 100663296);  //  25,165,824 ub, later aliased as Yt
    unsigned short* Wt   = (unsigned short*)(ws + 125829120);  //   3,538,944 Wt[2304][768] bf16
    unsigned short* W2t  = (unsigned short*)(ws + 129368064);  //   1,179,648 W2t[768][768] bf16
    float*          kfil = (float*)(ws + 130547712);           //   6,291,456 k[768][2048] fp32
    float2*         Kf   = (float2*)(ws + 136839168);          //  25,165,824 K_f[768][16][256] cplx (permuted, (FFT(k)+Db)/4096)

    static int attr_set = 0;
    if (!attr_set) {
        (void)hipFuncSetAttribute(reinterpret_cast<const void*>(gemm256_kernel),
                                  hipFuncAttributeMaxDynamicSharedMemorySize, 131072);
        attr_set = 1;
    }

    filter_k_kernel<<<512, 256, 0, stream>>>(z, sf, eo, eo_b, oo1, oo1_b, oo2, oo2_b, oh, kfil);
    filter_fft_kernel<<<768, 256, 0, stream>>>(kfil, D_bias, Kf);
    convert_u_kernel<<<12288, 256, 0, stream>>>(u, ubYt);
    transpose_W_kernel<<<dim3(72, 24), 256, 0, stream>>>(in_W, Wt, 768, 2304);
    transpose_W_kernel<<<dim3(24, 24), 256, 0, stream>>>(out_W, W2t, 768, 768);
    gemm256_kernel<<<dim3(64, 9), 512, 131072, stream>>>(Wt, ubYt, in_b, Xbf, nullptr, 0);
    fft_conv_kernel<<<dim3(768, 4), 256, 0, stream>>>(Xbf, Kf, x1_s, x2_s, v_s, x1_sb, x2_sb, v_sb, Ybf);
    transpose_Y_kernel<<<12288, 256, 0, stream>>>(Ybf, ubYt);
    gemm256_kernel<<<dim3(64, 3), 512, 131072, stream>>>(ubYt, W2t, out_b, nullptr, out, 1);
}

// Round 5
// 348.197 us; speedup vs baseline: 1.4270x; 1.0385x over previous
//
#include <hip/hip_runtime.h>

// ---------------------------------------------------------------------------
// FlashMMSequenceMixing (Hyena-style): B=8, L=2048, D=768, ORDER=128, FFT=4096
// R11 -> R12: GEMM retiled to kill grid-tail quantization (R11 counters:
// mode-0 = 576 blocks @ 1 block/CU = 2.25 rounds -> 3-round makespan, 25%
// idle; MfmaUtil 31%).
//  - mode 0: 192x256 tiles -> 12x64 = 768 blocks = exactly 3.0 rounds.
//  - mode 1: 256x192 tiles -> 64x4  = 256 blocks = exactly 1.0 round.
//  - LDS 112 KiB (2-buf BK=64). Template<TM,TN,WR,WC,MODE>.
//  - Schedule swapped to the simple 2-phase double-buffer (stage t+1 ->
//    compute t -> vmcnt(0)+lgkmcnt(0)+barrier): the 8-phase quarter schedule
//    doesn't survive 192-row tiles (quarters no longer align to wave halves).
//    Hazards: each buffer rewritten only after its readers' end-of-tile
//    barrier; every tile's 7 DMAs issued a full tile (~2000cyc) before the
//    drain; vmcnt==0 at exit.  Cost vs 8-phase ~10% (m248v2), tail gain 25%.
// fft_conv/filters unchanged from R11 (spill fix held; fft_conv < 77us).
// ---------------------------------------------------------------------------

typedef __bf16 bf16x8 __attribute__((ext_vector_type(8)));
typedef float  f32x4  __attribute__((ext_vector_type(4)));

#define AS1 __attribute__((address_space(1)))
#define AS3 __attribute__((address_space(3)))
#define GLD16(gp, lp) __builtin_amdgcn_global_load_lds((AS1 void*)(void*)(gp), (AS3 void*)(void*)(lp), 16, 0, 0)

// compiler-visible fences (memory clobber pins LDS/global ops to program order)
#define LGKM_BAR       __asm__ __volatile__("s_waitcnt lgkmcnt(0)\n\ts_barrier" ::: "memory")
#define VM_LGKM_BAR(N) __asm__ __volatile__("s_waitcnt vmcnt(" #N ") lgkmcnt(0)\n\ts_barrier" ::: "memory")

__device__ __forceinline__ unsigned short f2b(float f) {
    unsigned u = __builtin_bit_cast(unsigned, f);
    unsigned r = (u + 0x7fffu + ((u >> 16) & 1u)) >> 16;
    return (unsigned short)r;
}
__device__ __forceinline__ float b2f_lo(unsigned u) {
    return __builtin_bit_cast(float, u << 16);
}
__device__ __forceinline__ float b2f_hi(unsigned u) {
    return __builtin_bit_cast(float, u & 0xffff0000u);
}

__device__ __forceinline__ float2 cmul(float2 a, float2 b) {
    return make_float2(a.x * b.x - a.y * b.y, a.x * b.y + a.y * b.x);
}
__device__ __forceinline__ float2 cadd(float2 a, float2 b) { return make_float2(a.x + b.x, a.y + b.y); }
__device__ __forceinline__ float2 csub(float2 a, float2 b) { return make_float2(a.x - b.x, a.y - b.y); }

#define TWO_PI 6.283185307179586f

// ------------------------- 16-point register DFT ---------------------------
#define BFLY(i,j)   { float2 ta=x[i], tb=x[j]; x[i]=cadd(ta,tb); x[j]=csub(ta,tb); }
#define BFLYW(i,j,w){ float2 ta=x[i], tb=x[j]; x[i]=cadd(ta,tb); x[j]=cmul(csub(ta,tb),(w)); }
#define BFLYI(i,j)  { float2 ta=x[i], tb=x[j]; x[i]=cadd(ta,tb); float2 tt=csub(ta,tb); x[j]=make_float2(-dd*tt.y, dd*tt.x); }
#define CSWAP(i,j)  { float2 tt=x[i]; x[i]=x[j]; x[j]=tt; }

template<int DIR, bool UZ>
__device__ __forceinline__ void dft16(float2* x) {
    const float dd = (float)DIR;
    const float C1 = 0.92387953251128674f, S1 = 0.38268343236508977f, R2 = 0.70710678118654752f;
    const float2 W1 = make_float2( C1, dd*S1);
    const float2 W2 = make_float2( R2, dd*R2);
    const float2 W3 = make_float2( S1, dd*C1);
    const float2 W5 = make_float2(-S1, dd*C1);
    const float2 W6 = make_float2(-R2, dd*R2);
    const float2 W7 = make_float2(-C1, dd*S1);
    if (UZ) {
        x[8]  = x[0];
        x[9]  = cmul(x[1], W1);
        x[10] = cmul(x[2], W2);
        x[11] = cmul(x[3], W3);
        x[12] = make_float2(-dd*x[4].y, dd*x[4].x);
        x[13] = cmul(x[5], W5);
        x[14] = cmul(x[6], W6);
        x[15] = cmul(x[7], W7);
    } else {
        BFLY(0,8); BFLYW(1,9,W1); BFLYW(2,10,W2); BFLYW(3,11,W3);
        BFLYI(4,12); BFLYW(5,13,W5); BFLYW(6,14,W6); BFLYW(7,15,W7);
    }
    BFLY(0,4);  BFLYW(1,5,W2);  BFLYI(2,6);   BFLYW(3,7,W6);
    BFLY(8,12); BFLYW(9,13,W2); BFLYI(10,14); BFLYW(11,15,W6);
    BFLY(0,2);  BFLYI(1,3);  BFLY(4,6);   BFLYI(5,7);
    BFLY(8,10); BFLYI(9,11); BFLY(12,14); BFLYI(13,15);
    BFLY(0,1); BFLY(2,3); BFLY(4,5); BFLY(6,7);
    BFLY(8,9); BFLY(10,11); BFLY(12,13); BFLY(14,15);
    CSWAP(1,8); CSWAP(2,4); CSWAP(3,12); CSWAP(5,10); CSWAP(7,14); CSWAP(11,13);
}

// twiddle by power-split: x[4a+b] *= w^(4a) * w^b. 6 complex (12 VGPR) live.
__device__ __forceinline__ void twiddle16(float2* x, float ang) {
    float s, c; __sincosf(ang, &s, &c);
    const float2 u1  = make_float2(c, s);
    const float2 u2  = cmul(u1, u1);
    const float2 u3  = cmul(u2, u1);
    const float2 u4  = cmul(u2, u2);
    const float2 u8  = cmul(u4, u4);
    const float2 u12 = cmul(u8, u4);
    x[1]  = cmul(x[1],  u1);
    x[2]  = cmul(x[2],  u2);
    x[3]  = cmul(x[3],  u3);
    x[4]  = cmul(x[4],  u4);
    x[5]  = cmul(x[5],  cmul(u4, u1));
    x[6]  = cmul(x[6],  cmul(u4, u2));
    x[7]  = cmul(x[7],  cmul(u4, u3));
    x[8]  = cmul(x[8],  u8);
    x[9]  = cmul(x[9],  cmul(u8, u1));
    x[10] = cmul(x[10], cmul(u8, u2));
    x[11] = cmul(x[11], cmul(u8, u3));
    x[12] = cmul(x[12], u12);
    x[13] = cmul(x[13], cmul(u12, u1));
    x[14] = cmul(x[14], cmul(u12, u2));
    x[15] = cmul(x[15], cmul(u12, u3));
}

// physical LDS index (float2 units), XOR-swizzled exact-stride layouts.
__device__ __forceinline__ int ph1(int row, int col) { return row * 256 + (col ^ row); }
__device__ __forceinline__ int ph2(int row, int col) { return row * 16 + (col ^ (row & 15)); }

__device__ __forceinline__ void fft4096_fwd(float2* x, float2* lds, int t) {
    dft16<-1, true>(x);
    twiddle16(x, -(float)t * (TWO_PI / 4096.0f));
    #pragma unroll
    for (int k1 = 0; k1 < 16; ++k1) lds[ph1(k1, t)] = x[k1];
    __syncthreads();
    const int hi = t >> 4, lo = t & 15;
    #pragma unroll
    for (int t1 = 0; t1 < 16; ++t1) x[t1] = lds[ph1(hi, t1 * 16 + lo)];
    dft16<-1, false>(x);
    twiddle16(x, -(float)lo * (TWO_PI / 256.0f));
    __syncthreads();
    #pragma unroll
    for (int k2 = 0; k2 < 16; ++k2) lds[ph2(t, k2)] = x[k2];
    __syncthreads();
    #pragma unroll
    for (int t0 = 0; t0 < 16; ++t0) x[t0] = lds[ph2(hi * 16 + t0, lo)];
    dft16<-1, false>(x);
}

__device__ __forceinline__ void fft4096_inv(float2* x, float2* lds, int t) {
    const int hi = t >> 4, lo = t & 15;
    dft16<1, false>(x);
    __syncthreads();
    #pragma unroll
    for (int t0 = 0; t0 < 16; ++t0) lds[ph2(hi * 16 + t0, lo)] = x[t0];
    __syncthreads();
    #pragma unroll
    for (int k2 = 0; k2 < 16; ++k2) x[k2] = lds[ph2(t, k2)];
    twiddle16(x, (float)lo * (TWO_PI / 256.0f));
    dft16<1, false>(x);
    __syncthreads();
    #pragma unroll
    for (int t1 = 0; t1 < 16; ++t1) lds[ph1(hi, t1 * 16 + lo)] = x[t1];
    __syncthreads();
    #pragma unroll
    for (int k1 = 0; k1 < 16; ++k1) x[k1] = lds[ph1(k1, t)];
    twiddle16(x, (float)t * (TWO_PI / 4096.0f));
    dft16<1, false>(x);
}

// ------------------------------- filter MLP --------------------------------
__global__ __launch_bounds__(256) void filter_k_kernel(
    const float* __restrict__ z, const float* __restrict__ sf,
    const float* __restrict__ eo, const float* __restrict__ eo_b,
    const float* __restrict__ oo1, const float* __restrict__ oo1_b,
    const float* __restrict__ oo2, const float* __restrict__ oo2_b,
    const float* __restrict__ oh, float* __restrict__ kfil)
{
    __shared__ float h3buf[4][128];
    __shared__ float htmp[2][128];
    const int t = threadIdx.x;
    const int l0 = blockIdx.x * 4;
    const int half = t >> 7;
    const int o = t & 127;
    const float sfo = sf[o];
    for (int p = 0; p < 2; ++p) {
        const int li = p * 2 + half;
        const int l = l0 + li;
        float a = eo_b[o];
        #pragma unroll
        for (int e = 0; e < 5; ++e) a += z[l * 5 + e] * eo[e * 128 + o];
        htmp[half][o] = sinf(sfo * a);
        __syncthreads();
        float a2 = oo1_b[o];
        for (int q = 0; q < 128; ++q) a2 += htmp[half][q] * oo1[q * 128 + o];
        const float h2 = sinf(sfo * a2);
        __syncthreads();
        htmp[half][o] = h2;
        __syncthreads();
        float a3 = oo2_b[o];
        for (int q = 0; q < 128; ++q) a3 += htmp[half][q] * oo2[q * 128 + o];
        h3buf[li][o] = sinf(sfo * a3);
        __syncthreads();
    }
    const float MIND = -3.070113457325394f;
    const float MAXD = -15.350567286626972f;
    for (int c = 0; c < 3; ++c) {
        const int h = t + c * 256;
        float acc[4];
        #pragma unroll
        for (int li = 0; li < 4; ++li) acc[li] = 0.f;
        for (int q = 0; q < 128; ++q) {
            const float w = oh[q * 768 + h];
            #pragma unroll
            for (int li = 0; li < 4; ++li) acc[li] += h3buf[li][q] * w;
        }
        const float delta = fabsf(MIND + (MAXD - MIND) * (float)h * (1.0f / 767.0f));
        #pragma unroll
        for (int li = 0; li < 4; ++li) {
            const int l = l0 + li;
            const float tt = (float)l * (1.0f / 2047.0f);
            kfil[h * 2048 + l] = acc[li] * expf(-tt * delta);
        }
    }
}

// --------------------------- filter FFT ------------------------------------
// Stores Kf' = (FFT(k) + D_bias[d]) / 4096 (normalization + skip folded in).
__global__ __launch_bounds__(256) void filter_fft_kernel(
    const float* __restrict__ kfil, const float* __restrict__ D_bias,
    float2* __restrict__ Kf)
{
    __shared__ __align__(16) float2 lds[4096];
    const int d = blockIdx.x, t = threadIdx.x;
    float2 x[16];
    #pragma unroll
    for (int r = 0; r < 8; ++r) x[r] = make_float2(kfil[d * 2048 + r * 256 + t], 0.f);
    fft4096_fwd(x, lds, t);
    const float db = D_bias[d];
    const float s = 1.0f / 4096.0f;
    #pragma unroll
    for (int k3 = 0; k3 < 16; ++k3)
        Kf[d * 4096 + k3 * 256 + t] = make_float2((x[k3].x + db) * s, x[k3].y * s);
}

// --------------------------- conversions/transposes ------------------------
__global__ __launch_bounds__(256) void convert_u_kernel(
    const float* __restrict__ u, unsigned short* __restrict__ ub)
{
    const int g = blockIdx.x * 256 + threadIdx.x;
    const float4 v = ((const float4*)u)[g];
    uint2 o;
    o.x = (unsigned)f2b(v.x) | ((unsigned)f2b(v.y) << 16);
    o.y = (unsigned)f2b(v.z) | ((unsigned)f2b(v.w) << 16);
    ((uint2*)ub)[g] = o;
}

__global__ __launch_bounds__(256) void transpose_W_kernel(
    const float* __restrict__ W, unsigned short* __restrict__ Wt, int K, int N)
{
    __shared__ float tile[32][33];
    const int n0 = blockIdx.x * 32, k0 = blockIdx.y * 32;
    const int tx = threadIdx.x & 31, ty = threadIdx.x >> 5;
    #pragma unroll
    for (int r = 0; r < 4; ++r) {
        const int kk = ty + r * 8;
        tile[kk][tx] = W[(k0 + kk) * N + n0 + tx];
    }
    __syncthreads();
    #pragma unroll
    for (int r = 0; r < 4; ++r) {
        const int nn = ty + r * 8;
        Wt[(n0 + nn) * K + k0 + tx] = f2b(tile[tx][nn]);
    }
}

__global__ __launch_bounds__(256) void transpose_Y_kernel(
    const unsigned short* __restrict__ Y, unsigned short* __restrict__ Yt)
{
    __shared__ unsigned short tile[32][34];
    const int bx = blockIdx.x;
    const int l0 = (bx & 63) * 32;
    const int tmp = bx >> 6;
    const int d0 = (tmp % 24) * 32;
    const int b  = tmp / 24;
    const int tx = threadIdx.x & 31, ty = threadIdx.x >> 5;
    #pragma unroll
    for (int r = 0; r < 4; ++r) {
        const int dd = ty + r * 8;
        tile[dd][tx] = Y[(b * 768 + d0 + dd) * 2048 + l0 + tx];
    }
    __syncthreads();
    #pragma unroll
    for (int r = 0; r < 4; ++r) {
        const int ll = ty + r * 8;
        Yt[(b * 2048 + l0 + ll) * 768 + d0 + tx] = tile[tx][ll];
    }
}

// ------------------------------- bf16 GEMM ---------------------------------
// TMxTN tile, BK=64, 8 waves (WRxWC), 2-phase double-buffered K-loop.
// K = 768 = 12 tiles of 64.  Per tile: {stage next tile into other buf;
// ds_read frags + MFMA (ks=0,1); s_waitcnt vmcnt(0) lgkmcnt(0); s_barrier}.
// Buffer rewritten only after its readers' end-of-tile barrier; tile DMAs
// issued a full tile before their drain; vmcnt==0 at exit.
// LDS: As[2][TM][64], Bs[2][TN][64] bf16, XOR chunk swizzle: LDS slot
// (row, c) holds data chunk c ^ (row&7) (16B chunks; linear DMA dest,
// pre-swizzled global source).
// MODE 0: grid (TN-tiles, TM-tiles), bf16 out to X[part][b][768][2048].
// MODE 1: grid (TM-tiles, TN-tiles), f32 out [M][768].
template<int TM, int TN, int WR, int WC, int MODE>
__global__ __launch_bounds__(512, 2) void gemm2ph_kernel(
    const unsigned short* __restrict__ A,
    const unsigned short* __restrict__ Bm,
    const float* __restrict__ bias,
    unsigned short* __restrict__ outb,
    float* __restrict__ outf)
{
    constexpr int MF = TM / WR / 16;   // m-frags per wave
    constexpr int NF = TN / WC / 16;   // n-frags per wave
    constexpr int QA = TM / 64;        // A 64-row DMA quarters
    constexpr int QB = TN / 64;        // B 64-row DMA quarters
    extern __shared__ __align__(16) unsigned short lds[];
    unsigned short* As = lds;                    // [2][TM][64]
    unsigned short* Bs = lds + 2 * TM * 64;      // [2][TN][64]
    const int t = threadIdx.x;
    const int wv = t >> 6, lane = t & 63;
    const int row0 = (MODE == 0 ? blockIdx.y : blockIdx.x) * TM;
    const int col0 = (MODE == 0 ? blockIdx.x : blockIdx.y) * TN;
    const int wr = wv / WC, wc = wv % WC;
    const int frow = lane & 15, kc = lane >> 4;

    f32x4 acc[MF][NF] = {};

    // staging: thread t covers (row = q*64 + (t>>3), slot = t&7); slot holds
    // data chunk (t&7) ^ (row&7).
    const int srow = t >> 3;
    const int cdat = (t & 7) ^ (srow & 7);
    const unsigned short* gA = A  + (row0 + srow) * 768 + cdat * 8;
    const unsigned short* gB = Bm + (col0 + srow) * 768 + cdat * 8;

#define STAGE(buf, kt)                                                        \
    {                                                                         \
        _Pragma("unroll") for (int q = 0; q < QA; ++q)                        \
            GLD16(gA + q * 49152 + (kt) * 64,                                 \
                  (char*)As + (buf) * (TM * 128) + q * 8192 + wv * 1024);     \
        _Pragma("unroll") for (int q = 0; q < QB; ++q)                        \
            GLD16(gB + q * 49152 + (kt) * 64,                                 \
                  (char*)Bs + (buf) * (TN * 128) + q * 8192 + wv * 1024);     \
    }

    // one K-sub-step (K=32): read frags (swizzle-matched) + MFMA
#define HALF(buf, ks)                                                         \
    {                                                                         \
        bf16x8 aF[MF], bF[NF];                                                \
        _Pragma("unroll") for (int m = 0; m < MF; ++m) {                      \
            const int r = wr * (TM / WR) + m * 16 + frow;                     \
            aF[m] = *(const bf16x8*)(As + (buf) * (TM * 64) + r * 64 +        \
                                     ((((ks) * 4 + kc) ^ (r & 7)) << 3));     \
        }                                                                     \
        _Pragma("unroll") for (int n = 0; n < NF; ++n) {                      \
            const int r = wc * (TN / WC) + n * 16 + frow;                     \
            bF[n] = *(const bf16x8*)(Bs + (buf) * (TN * 64) + r * 64 +        \
                                     ((((ks) * 4 + kc) ^ (r & 7)) << 3));     \
        }                                                                     \
        __builtin_amdgcn_s_setprio(1);                                        \
        _Pragma("unroll") for (int m = 0; m < MF; ++m)                        \
        _Pragma("unroll") for (int n = 0; n < NF; ++n)                        \
            acc[m][n] = __builtin_amdgcn_mfma_f32_16x16x32_bf16(              \
                aF[m], bF[n], acc[m][n], 0, 0, 0);                            \
        __builtin_amdgcn_s_setprio(0);                                        \
    }

    // prologue: tiles 0 and 1
    STAGE(0, 0);
    STAGE(1, 1);
    VM_LGKM_BAR(7);            // oldest QA+QB(=7) = tile 0 landed

    // tile 0 (no staging this tile; tile 1 already in flight)
    HALF(0, 0); HALF(0, 1);
    VM_LGKM_BAR(0);            // tile 1 landed; buf0 readers done

    // tiles 1..10, staging tiles 2..11
    #pragma unroll 1
    for (int kt = 1; kt <= 9; kt += 2) {
        STAGE(0, kt + 1);      // buf0's readers (tile kt-1) done at last bar
        HALF(1, 0); HALF(1, 1);
        VM_LGKM_BAR(0);
        STAGE(1, kt + 2);
        HALF(0, 0); HALF(0, 1);
        VM_LGKM_BAR(0);
    }

    // tile 11 (buf1, landed at the last barrier; nothing in flight)
    HALF(1, 0); HALF(1, 1);
#undef STAGE
#undef HALF

    if (MODE == 0) {
        const int part = row0 / 768;       // TM=192: 768%192==0, no straddle
        const int bb = col0 / 2048;        // TN=256: 2048%256==0
        unsigned short* Xp = outb + (size_t)(part * 8 + bb) * 768 * 2048;
        const int drow0 = row0 - part * 768 + wr * (TM / WR) + kc * 4;
        const int lcol0 = col0 - bb * 2048 + wc * (TN / WC) + frow;
        #pragma unroll
        for (int m = 0; m < MF; ++m) {
            #pragma unroll
            for (int rr = 0; rr < 4; ++rr) {
                const int dd = drow0 + m * 16 + rr;
                const float bn = bias[row0 + wr * (TM / WR) + kc * 4 + m * 16 + rr];
                #pragma unroll
                for (int n = 0; n < NF; ++n)
                    Xp[dd * 2048 + lcol0 + n * 16] = f2b(acc[m][n][rr] + bn);
            }
        }
    } else {
        #pragma unroll
        for (int m = 0; m < MF; ++m) {
            #pragma unroll
            for (int rr = 0; rr < 4; ++rr) {
                const int mm = row0 + wr * (TM / WR) + kc * 4 + m * 16 + rr;
                #pragma unroll
                for (int n = 0; n < NF; ++n) {
                    const int nn = col0 + wc * (TN / WC) + n * 16 + frow;
                    outf[(size_t)mm * 768 + nn] = acc[m][n][rr] + bias[nn];
                }
            }
        }
    }
}

// --------------------- fused conv4 + gate + FFT conv -----------------------
__device__ __forceinline__ void conv6(const unsigned short* __restrict__ p,
                                      const float* w, float bias, int t, float* out8)
{
    const uint4 m = *(const uint4*)(p + 8 * t);
    uint2 q = make_uint2(0u, 0u);
    if (t) q = *(const uint2*)(p + 8 * t - 4);
    float s[12];
    s[0] = b2f_lo(q.x); s[1] = b2f_hi(q.x); s[2] = b2f_lo(q.y); s[3] = b2f_hi(q.y);
    s[4] = b2f_lo(m.x); s[5] = b2f_hi(m.x); s[6] = b2f_lo(m.y); s[7] = b2f_hi(m.y);
    s[8] = b2f_lo(m.z); s[9] = b2f_hi(m.z); s[10] = b2f_lo(m.w); s[11] = b2f_hi(m.w);
    #pragma unroll
    for (int i = 0; i < 8; ++i)
        out8[i] = bias + w[0] * s[i + 1] + w[1] * s[i + 2] + w[2] * s[i + 3] + w[3] * s[i + 4];
}

// grid (768, 4): x=d (same-d blocks 768 apart -> same XCD -> Kf L2 reuse)
__global__ __launch_bounds__(256) void fft_conv_kernel(
    const unsigned short* __restrict__ X, const float2* __restrict__ Kf,
    const float* __restrict__ x1_s, const float* __restrict__ x2_s, const float* __restrict__ v_s,
    const float* __restrict__ x1_sb, const float* __restrict__ x2_sb, const float* __restrict__ v_sb,
    unsigned short* __restrict__ Y)
{
    __shared__ __align__(16) float2 lds[4096];
    unsigned* ldsu = (unsigned*)lds;
    const int d = blockIdx.x, jp = blockIdx.y, t = threadIdx.x;
    const int b0 = jp * 2, b1 = b0 + 1;

    const unsigned short* px1a = X + ((size_t)(0 * 8 + b0) * 768 + d) * 2048;
    const unsigned short* pva  = X + ((size_t)(2 * 8 + b0) * 768 + d) * 2048;
    const unsigned short* px1b = X + ((size_t)(0 * 8 + b1) * 768 + d) * 2048;
    const unsigned short* pvb  = X + ((size_t)(2 * 8 + b1) * 768 + d) * 2048;

    // ---- v * x1 gate, b0 then b1 (halved live set), pack pairs into LDS ----
    {
        float w1[4], wv[4];
        #pragma unroll
        for (int j = 0; j < 4; ++j) { w1[j] = x1_s[d * 4 + j]; wv[j] = v_s[d * 4 + j]; }
        const float bc1 = x1_sb[d], bcv = v_sb[d];
        float pa[8];
        {
            float va[8], g[8];
            conv6(pva,  wv, bcv, t, va);
            conv6(px1a, w1, bc1, t, g);
            #pragma unroll
            for (int i = 0; i < 8; ++i) pa[i] = va[i] * g[i];
        }
        {
            float vb[8], g[8];
            conv6(pvb,  wv, bcv, t, vb);
            conv6(px1b, w1, bc1, t, g);
            unsigned vh[8];
            #pragma unroll
            for (int i = 0; i < 8; ++i)
                vh[i] = (unsigned)f2b(pa[i]) | ((unsigned)f2b(vb[i] * g[i]) << 16);
            *(uint4*)(ldsu + 8 * t)     = make_uint4(vh[0], vh[1], vh[2], vh[3]);
            *(uint4*)(ldsu + 8 * t + 4) = make_uint4(vh[4], vh[5], vh[6], vh[7]);
        }
    }
    __syncthreads();

    float2 x[16];
    #pragma unroll
    for (int r = 0; r < 8; ++r) {
        const unsigned u = ldsu[r * 256 + t];
        x[r] = make_float2(b2f_lo(u), b2f_hi(u));
    }
    __syncthreads();

    fft4096_fwd(x, lds, t);

    // pointwise multiply by Kf' (= (FFT(k)+Db)/4096); 4-wide chunks with
    // fences so the compiler doesn't hoist 16 loads into 32 live regs.
    {
        const float2* kf = Kf + (size_t)d * 4096;
        #pragma unroll
        for (int c4 = 0; c4 < 4; ++c4) {
            float2 kr[4];
            #pragma unroll
            for (int j = 0; j < 4; ++j) kr[j] = kf[(c4 * 4 + j) * 256 + t];
            #pragma unroll
            for (int j = 0; j < 4; ++j) x[c4 * 4 + j] = cmul(x[c4 * 4 + j], kr[j]);
            __asm__ __volatile__("" ::: "memory");
        }
    }

    fft4096_inv(x, lds, t);

    // ---- x2 gate: recompute, transpose through LDS, apply, store ----
    __syncthreads();   // all lanes done with inv-FFT's final LDS reads
    {
        const unsigned short* px2a = X + ((size_t)(1 * 8 + b0) * 768 + d) * 2048;
        const unsigned short* px2b = X + ((size_t)(1 * 8 + b1) * 768 + d) * 2048;
        float w2[4];
        #pragma unroll
        for (int j = 0; j < 4; ++j) w2[j] = x2_s[d * 4 + j];
        const float bc2 = x2_sb[d];
        float ga[8], gb[8];
        conv6(px2a, w2, bc2, t, ga);
        conv6(px2b, w2, bc2, t, gb);
        unsigned c2[8];
        #pragma unroll
        for (int i = 0; i < 8; ++i)
            c2[i] = (unsigned)f2b(ga[i]) | ((unsigned)f2b(gb[i]) << 16);
        *(uint4*)(ldsu + 8 * t)     = make_uint4(c2[0], c2[1], c2[2], c2[3]);
        *(uint4*)(ldsu + 8 * t + 4) = make_uint4(c2[4], c2[5], c2[6], c2[7]);
    }
    __syncthreads();

    unsigned short* ya = Y + ((size_t)b0 * 768 + d) * 2048;
    unsigned short* yb = Y + ((size_t)b1 * 768 + d) * 2048;
    #pragma unroll
    for (int n1 = 0; n1 < 8; ++n1) {
        const int l = n1 * 256 + t;
        const unsigned u = ldsu[l];
        ya[l] = f2b(x[n1].x * b2f_lo(u));
        yb[l] = f2b(x[n1].y * b2f_hi(u));
    }
}

// --------------------------------- launch ----------------------------------
extern "C" void kernel_launch(void* const* d_in, const int* in_sizes, int n_in,
                              void* d_out, int out_size, void* d_ws, size_t ws_size,
                              hipStream_t stream)
{
    (void)in_sizes; (void)n_in; (void)out_size; (void)ws_size;
    const float* u      = (const float*)d_in[0];
    const float* in_W   = (const float*)d_in[1];
    const float* in_b   = (const float*)d_in[2];
    const float* out_W  = (const float*)d_in[3];
    const float* out_b  = (const float*)d_in[4];
    const float* x1_s   = (const float*)d_in[5];
    const float* x2_s   = (const float*)d_in[6];
    const float* v_s    = (const float*)d_in[7];
    const float* x1_sb  = (const float*)d_in[8];
    const float* x2_sb  = (const float*)d_in[9];
    const float* v_sb   = (const float*)d_in[10];
    const float* D_bias = (const float*)d_in[11];
    const float* z      = (const float*)d_in[12];
    const float* sf     = (const float*)d_in[13];
    const float* eo     = (const float*)d_in[14];
    const float* eo_b   = (const float*)d_in[15];
    const float* oo1    = (const float*)d_in[16];
    const float* oo1_b  = (const float*)d_in[17];
    const float* oo2    = (const float*)d_in[18];
    const float* oo2_b  = (const float*)d_in[19];
    const float* oh     = (const float*)d_in[20];
    float* out = (float*)d_out;

    char* ws = (char*)d_ws;
    unsigned short* Xbf  = (unsigned short*)(ws + 0);          //  75,497,472 X[3][8][768][2048] bf16
    unsigned short* Ybf  = (unsigned short*)(ws + 75497472);   //  25,165,824 Y[8][768][2048] bf16
    unsigned short* ubYt = (unsigned short*)(ws + 100663296);  //  25,165,824 ub, later aliased as Yt
    unsigned short* Wt   = (unsigned short*)(ws + 125829120);  //   3,538,944 Wt[2304][768] bf16
    unsigned short* W2t  = (unsigned short*)(ws + 129368064);  //   1,179,648 W2t[768][768] bf16
    float*          kfil = (float*)(ws + 130547712);           //   6,291,456 k[768][2048] fp32
    float2*         Kf   = (float2*)(ws + 136839168);          //  25,165,824 K_f[768][16][256] cplx (permuted, (FFT(k)+Db)/4096)

    static int attr_set = 0;
    if (!attr_set) {
        (void)hipFuncSetAttribute(
            reinterpret_cast<const void*>(&gemm2ph_kernel<192, 256, 2, 4, 0>),
            hipFuncAttributeMaxDynamicSharedMemorySize, 114688);
        (void)hipFuncSetAttribute(
            reinterpret_cast<const void*>(&gemm2ph_kernel<256, 192, 4, 2, 1>),
            hipFuncAttributeMaxDynamicSharedMemorySize, 114688);
        attr_set = 1;
    }

    filter_k_kernel<<<512, 256, 0, stream>>>(z, sf, eo, eo_b, oo1, oo1_b, oo2, oo2_b, oh, kfil);
    filter_fft_kernel<<<768, 256, 0, stream>>>(kfil, D_bias, Kf);
    convert_u_kernel<<<12288, 256, 0, stream>>>(u, ubYt);
    transpose_W_kernel<<<dim3(72, 24), 256, 0, stream>>>(in_W, Wt, 768, 2304);
    transpose_W_kernel<<<dim3(24, 24), 256, 0, stream>>>(out_W, W2t, 768, 768);
    // mode 0: 12 row-tiles(192) x 64 col-tiles(256) = 768 blocks = 3.0 rounds
    gemm2ph_kernel<192, 256, 2, 4, 0><<<dim3(64, 12), 512, 114688, stream>>>(
        Wt, ubYt, in_b, Xbf, nullptr);
    fft_conv_kernel<<<dim3(768, 4), 256, 0, stream>>>(Xbf, Kf, x1_s, x2_s, v_s, x1_sb, x2_sb, v_sb, Ybf);
    transpose_Y_kernel<<<12288, 256, 0, stream>>>(Ybf, ubYt);
    // mode 1: 64 row-tiles(256) x 4 col-tiles(192) = 256 blocks = 1.0 round
    gemm2ph_kernel<256, 192, 4, 2, 1><<<dim3(64, 4), 512, 114688, stream>>>(
        ubYt, W2t, out_b, nullptr, out);
}